// Round 11
// baseline (702.421 us; speedup 1.0000x reference)
//
#include <hip/hip_runtime.h>

#define BLK 256
#define BSHIFT 10
#define BSIZE 1024           // nodes per dst bucket (local index: 10 bits)
#define NSLICE 1024          // edge slices for hist/scatter
#define SCAN_T 512           // max K supported by single-block scan
#define KPAD 256             // max buckets (scan width in scatter kernels)
#define EPT 8                // edges per thread per tile in scatter kernels
#define TILE (BLK * EPT)     // 2048 edges staged per tile
#define T2SHIFT 11
#define TSIZE2 2048          // src-tile nodes for locality sort (16 KB of pin)
#define NT2MAX 128           // max src tiles
#define R2 8                 // sub-slices per bucket in second-level sort
#define SCAN2_T 1024         // scan width for k_scan2 (NT2*R2 <= 1024)

typedef int iv4 __attribute__((ext_vector_type(4)));   // clang vector: nt-load legal

template <typename T>
__device__ __forceinline__ T ntload(const T* p) { return __builtin_nontemporal_load(p); }

__device__ __forceinline__ iv4 ntload4(const int* p) {
    return __builtin_nontemporal_load((const iv4*)p);
}

// ---------------- level-1: bucket by dst (no global atomics) ----------------

__global__ void k_hist(const int* __restrict__ dst, int* __restrict__ partial,
                       int E, int chunk, int K) {
    extern __shared__ int cnt[];
    int s = blockIdx.x;
    for (int i = threadIdx.x; i < K; i += BLK) cnt[i] = 0;
    __syncthreads();
    int lo = s * chunk, hi = min(E, lo + chunk);
    for (int i = lo + threadIdx.x; i < hi; i += BLK)
        atomicAdd(&cnt[((unsigned)ntload(dst + i)) >> BSHIFT], 1);
    __syncthreads();
    int* prow = partial + (size_t)s * K;
    for (int i = threadIdx.x; i < K; i += BLK) prow[i] = cnt[i];
}

__global__ void __launch_bounds__(NSLICE) k_colscan(int* __restrict__ partial,
                                                    int* __restrict__ totals, int K) {
    __shared__ int sh[NSLICE];
    int k = blockIdx.x;
    int t = threadIdx.x;
    int v = partial[(size_t)t * K + k];
    sh[t] = v;
    __syncthreads();
    for (int off = 1; off < NSLICE; off <<= 1) {
        int u = (t >= off) ? sh[t - off] : 0;
        __syncthreads();
        sh[t] += u;
        __syncthreads();
    }
    partial[(size_t)t * K + k] = sh[t] - v;
    if (t == NSLICE - 1) totals[k] = sh[t];
}

__global__ void k_base(const int* __restrict__ totals, int* __restrict__ base, int K) {
    __shared__ int sh[SCAN_T];
    int t = threadIdx.x;
    int v = (t < K) ? totals[t] : 0;
    sh[t] = v;
    __syncthreads();
    for (int off = 1; off < SCAN_T; off <<= 1) {
        int u = (t >= off) ? sh[t - off] : 0;
        __syncthreads();
        sh[t] += u;
        __syncthreads();
    }
    if (t < K) base[t + 1] = sh[t];
    if (t == 0) base[0] = 0;
}

// tile counting-sort scatter: packed = (dst_local << sbits) | src
__global__ void __launch_bounds__(BLK) k_scatter(const int* __restrict__ src,
                                                 const int* __restrict__ dst,
                                                 const int* __restrict__ offs,
                                                 const int* __restrict__ base,
                                                 int* __restrict__ packed,
                                                 int E, int chunk, int K, int sbits) {
    __shared__ int cnt[KPAD];
    __shared__ int scn[KPAD];
    __shared__ int gstart[KPAD];
    __shared__ int cur[KPAD];
    __shared__ int stageval[TILE];
    __shared__ int stageaddr[TILE];
    int s = blockIdx.x;
    int tid = threadIdx.x;
    const int* orow = offs + (size_t)s * K;
    if (tid < K) cur[tid] = orow[tid] + base[tid];
    int lo = s * chunk, hi = min(E, lo + chunk);

    for (int tlo = lo; tlo < hi; tlo += TILE) {
        for (int k2 = tid; k2 < KPAD; k2 += BLK) cnt[k2] = 0;
        __syncthreads();

        int kk[EPT], rr[EPT], vv[EPT];
#pragma unroll
        for (int j = 0; j < EPT; ++j) {
            int i = tlo + j * BLK + tid;
            kk[j] = -1;
            if (i < hi) {
                int d = ntload(dst + i);
                int sc = ntload(src + i);
                kk[j] = ((unsigned)d) >> BSHIFT;
                vv[j] = ((d & (BSIZE - 1)) << sbits) | sc;
                rr[j] = atomicAdd(&cnt[kk[j]], 1);
            }
        }
        __syncthreads();

        int c = cnt[tid];
        scn[tid] = c;
        __syncthreads();
        for (int off = 1; off < KPAD; off <<= 1) {
            int u = (tid >= off) ? scn[tid - off] : 0;
            __syncthreads();
            scn[tid] += u;
            __syncthreads();
        }
        scn[tid] -= c;
        gstart[tid] = cur[tid];
        cur[tid] += c;
        __syncthreads();

#pragma unroll
        for (int j = 0; j < EPT; ++j) {
            if (kk[j] >= 0) {
                int idx = scn[kk[j]] + rr[j];
                stageval[idx]  = vv[j];
                stageaddr[idx] = gstart[kk[j]] + rr[j];
            }
        }
        __syncthreads();

        int tot = min(hi - tlo, TILE);
        for (int i2 = tid; i2 < tot; i2 += BLK)
            packed[stageaddr[i2]] = stageval[i2];
        __syncthreads();
    }
}

// ---------------- level-2: sort each bucket's edges by src tile -------------

// per (bucket, slice) histogram of src tiles -> h2[b][NT2]
__global__ void k_hist2(const int* __restrict__ packed, const int* __restrict__ base,
                        int* __restrict__ h2, int NT2, int smask) {
    __shared__ int cnt[NT2MAX];
    int b = blockIdx.x;              // k*R2 + r
    int k = b / R2, r = b - k * R2;
    for (int i = threadIdx.x; i < NT2MAX; i += BLK) cnt[i] = 0;
    __syncthreads();
    int lo = base[k], len = base[k + 1] - lo;
    int s0 = lo + (int)(((long long)len * r) / R2);
    int s1 = lo + (int)(((long long)len * (r + 1)) / R2);
    for (int i = s0 + threadIdx.x; i < s1; i += BLK) {
        unsigned v = (unsigned)ntload(packed + i);
        atomicAdd(&cnt[(v & smask) >> T2SHIFT], 1);
    }
    __syncthreads();
    int* hrow = h2 + (size_t)b * NT2;
    for (int t = threadIdx.x; t < NT2; t += BLK) hrow[t] = cnt[t];
}

// per-bucket scan over (tile-major, slice-minor): h2 -> absolute offsets; grpoff2[k][t]
__global__ void __launch_bounds__(SCAN2_T) k_scan2(int* __restrict__ h2,
                                                   const int* __restrict__ base,
                                                   int* __restrict__ grpoff2, int NT2) {
    __shared__ int sh[SCAN2_T];
    int k = blockIdx.x;
    int t = threadIdx.x;
    int n = NT2 * R2;
    int v = 0;
    int tt = t / R2, r = t - tt * R2;
    if (t < n) v = h2[((size_t)(k * R2 + r)) * NT2 + tt];
    sh[t] = v;
    __syncthreads();
    for (int off = 1; off < SCAN2_T; off <<= 1) {
        int u = (t >= off) ? sh[t - off] : 0;
        __syncthreads();
        sh[t] += u;
        __syncthreads();
    }
    int excl = sh[t] - v + base[k];
    if (t < n) {
        h2[((size_t)(k * R2 + r)) * NT2 + tt] = excl;
        if (r == 0) grpoff2[(size_t)k * (NT2 + 1) + tt] = excl;
    }
    if (t == 0) grpoff2[(size_t)k * (NT2 + 1) + NT2] = base[k + 1];
}

// counting-sort each (bucket, slice) by src tile; burst-flush coalesced
__global__ void __launch_bounds__(BLK) k_scatter2(const int* __restrict__ packed,
                                                  const int* __restrict__ base,
                                                  const int* __restrict__ h2,
                                                  int* __restrict__ packed2,
                                                  int NT2, int smask) {
    __shared__ int cnt[KPAD];
    __shared__ int scn[KPAD];
    __shared__ int gstart[NT2MAX];
    __shared__ int cur[NT2MAX];
    __shared__ int stageval[TILE];
    __shared__ int stageaddr[TILE];
    int b = blockIdx.x;              // k*R2 + r
    int k = b / R2, r = b - k * R2;
    int tid = threadIdx.x;
    const int* hrow = h2 + (size_t)b * NT2;
    if (tid < NT2) cur[tid] = hrow[tid];
    int lo = base[k], len = base[k + 1] - lo;
    int s0 = lo + (int)(((long long)len * r) / R2);
    int s1 = lo + (int)(((long long)len * (r + 1)) / R2);

    for (int tlo = s0; tlo < s1; tlo += TILE) {
        for (int j = tid; j < KPAD; j += BLK) cnt[j] = 0;
        __syncthreads();

        int kk[EPT], rr[EPT], vv[EPT];
#pragma unroll
        for (int j = 0; j < EPT; ++j) {
            int i = tlo + j * BLK + tid;
            kk[j] = -1;
            if (i < s1) {
                int v = ntload(packed + i);
                vv[j] = v;
                kk[j] = (((unsigned)v) & smask) >> T2SHIFT;
                rr[j] = atomicAdd(&cnt[kk[j]], 1);
            }
        }
        __syncthreads();

        int c = cnt[tid];
        scn[tid] = c;
        __syncthreads();
        for (int off = 1; off < KPAD; off <<= 1) {
            int u = (tid >= off) ? scn[tid - off] : 0;
            __syncthreads();
            scn[tid] += u;
            __syncthreads();
        }
        scn[tid] -= c;
        if (tid < NT2) { gstart[tid] = cur[tid]; cur[tid] += c; }
        __syncthreads();

#pragma unroll
        for (int j = 0; j < EPT; ++j) {
            if (kk[j] >= 0) {
                int idx = scn[kk[j]] + rr[j];
                stageval[idx]  = vv[j];
                stageaddr[idx] = gstart[kk[j]] + rr[j];
            }
        }
        __syncthreads();

        int tot = min(s1 - tlo, TILE);
        for (int i2 = tid; i2 < tot; i2 += BLK)
            packed2[stageaddr[i2]] = stageval[i2];
        __syncthreads();
    }
}

// ---------------- aggregation ----------------

// degree counts -> degpart[b][BSIZE]  (level-1 packed; order irrelevant)
__global__ void k_deg(const int* __restrict__ packed, const int* __restrict__ base,
                      int M, int* __restrict__ degpart, int sbits) {
    __shared__ int cnt[BSIZE];
    int b = blockIdx.x;
    int k = b / M, m = b - k * M;
    for (int i = threadIdx.x; i < BSIZE; i += BLK) cnt[i] = 0;
    __syncthreads();
    int lo = base[k], len = base[k + 1] - lo;
    int l0 = lo + (int)(((long long)len * m) / M);
    int l1 = lo + (int)(((long long)len * (m + 1)) / M);
    int a0 = min((l0 + 3) & ~3, l1);
    int a1 = max(l1 & ~3, a0);
    for (int i = l0 + threadIdx.x; i < a0; i += BLK)
        atomicAdd(&cnt[((unsigned)ntload(packed + i)) >> sbits], 1);
    for (int i = a0 + 4 * threadIdx.x; i < a1; i += 4 * BLK) {
        iv4 q = ntload4(packed + i);
        atomicAdd(&cnt[((unsigned)q.x) >> sbits], 1);
        atomicAdd(&cnt[((unsigned)q.y) >> sbits], 1);
        atomicAdd(&cnt[((unsigned)q.z) >> sbits], 1);
        atomicAdd(&cnt[((unsigned)q.w) >> sbits], 1);
    }
    for (int i = a1 + threadIdx.x; i < l1; i += BLK)
        atomicAdd(&cnt[((unsigned)ntload(packed + i)) >> sbits], 1);
    __syncthreads();
    int* outp = degpart + (size_t)b * BSIZE;
    for (int i = threadIdx.x; i < BSIZE; i += BLK) outp[i] = cnt[i];
}

// edge body shared by both agg variants
__device__ __forceinline__ void agg_body(const int* __restrict__ edges,
                                         int l0, int l1,
                                         const float2* __restrict__ pin,
                                         float* accx, float* accy,
                                         int sbits, int smask) {
    int a0 = min((l0 + 3) & ~3, l1);
    int a1 = max(l1 & ~3, a0);
    for (int i = l0 + threadIdx.x; i < a0; i += BLK) {
        unsigned v = (unsigned)ntload(edges + i);
        float2 pv = pin[v & smask];
        int l = v >> sbits;
        atomicAdd(&accx[l], pv.x);
        atomicAdd(&accy[l], pv.y);
    }
    int i = a0 + 4 * threadIdx.x;
    if (i < a1) {
        iv4 q = ntload4(edges + i);
        for (; i < a1;) {
            int inext = i + 4 * BLK;
            iv4 qn;
            if (inext < a1) qn = ntload4(edges + inext);
            unsigned v0 = q.x, v1 = q.y, v2 = q.z, v3 = q.w;
            float2 e0 = pin[v0 & smask];
            float2 e1 = pin[v1 & smask];
            float2 e2 = pin[v2 & smask];
            float2 e3 = pin[v3 & smask];
            int l0i = v0 >> sbits, l1i = v1 >> sbits, l2i = v2 >> sbits, l3i = v3 >> sbits;
            atomicAdd(&accx[l0i], e0.x); atomicAdd(&accy[l0i], e0.y);
            atomicAdd(&accx[l1i], e1.x); atomicAdd(&accy[l1i], e1.y);
            atomicAdd(&accx[l2i], e2.x); atomicAdd(&accy[l2i], e2.y);
            atomicAdd(&accx[l3i], e3.x); atomicAdd(&accy[l3i], e3.y);
            q = qn;
            i = inext;
        }
    }
    for (int j = a1 + threadIdx.x; j < l1; j += BLK) {
        unsigned v = (unsigned)ntload(edges + j);
        float2 pv = pin[v & smask];
        int l = v >> sbits;
        atomicAdd(&accx[l], pv.x);
        atomicAdd(&accy[l], pv.y);
    }
}

// src-tile-sorted agg: sub-block m takes whole tile groups (L1-coherent window)
__global__ void __launch_bounds__(BLK) k_agg2(const int* __restrict__ packed2,
                                              const int* __restrict__ grpoff2,
                                              int M, int NT2,
                                              const float2* __restrict__ pin,
                                              float* __restrict__ partial,
                                              int sbits, int smask) {
    __shared__ float accx[BSIZE];
    __shared__ float accy[BSIZE];
    int b = blockIdx.x;
    int k = b / M, m = b - k * M;
    for (int i = threadIdx.x; i < BSIZE; i += BLK) { accx[i] = 0.f; accy[i] = 0.f; }
    __syncthreads();
    const int* go = grpoff2 + (size_t)k * (NT2 + 1);
    int t0 = (NT2 * m) / M, t1 = (NT2 * (m + 1)) / M;
    agg_body(packed2, go[t0], go[t1], pin, accx, accy, sbits, smask);
    __syncthreads();
    float* outp = partial + (size_t)b * (BSIZE * 2);
    for (int j = threadIdx.x * 2; j < BSIZE; j += BLK * 2) {
        float4 o = make_float4(accx[j], accy[j], accx[j + 1], accy[j + 1]);
        *(float4*)(outp + 2 * j) = o;
    }
}

// fallback: unsorted gather agg (when ws too small for level-2)
__global__ void __launch_bounds__(BLK) k_agg(const int* __restrict__ packed,
                                             const int* __restrict__ base,
                                             int M, const float2* __restrict__ pin,
                                             float* __restrict__ partial,
                                             int sbits, int smask) {
    __shared__ float accx[BSIZE];
    __shared__ float accy[BSIZE];
    int b = blockIdx.x;
    int k = b / M, m = b - k * M;
    for (int i = threadIdx.x; i < BSIZE; i += BLK) { accx[i] = 0.f; accy[i] = 0.f; }
    __syncthreads();
    int lo = base[k], len = base[k + 1] - lo;
    int l0 = lo + (int)(((long long)len * m) / M);
    int l1 = lo + (int)(((long long)len * (m + 1)) / M);
    agg_body(packed, l0, l1, pin, accx, accy, sbits, smask);
    __syncthreads();
    float* outp = partial + (size_t)b * (BSIZE * 2);
    for (int j = threadIdx.x * 2; j < BSIZE; j += BLK * 2) {
        float4 o = make_float4(accx[j], accy[j], accx[j + 1], accy[j + 1]);
        *(float4*)(outp + 2 * j) = o;
    }
}

// ---------------- node epilogues ----------------

__global__ void k_node1(const int* __restrict__ degpart, int M,
                        const float* __restrict__ x, const float* __restrict__ W1,
                        float* __restrict__ dinv, float2* __restrict__ p1, int N) {
    int i = blockIdx.x * BLK + threadIdx.x;
    if (i >= N) return;
    int k = i >> BSHIFT, l = i & (BSIZE - 1);
    int c = 0;
    for (int m = 0; m < M; ++m) c += degpart[((size_t)(k * M + m)) * BSIZE + l];
    float di = rsqrtf((float)c + 1.0f);
    dinv[i] = di;
    float2 xv = ((const float2*)x)[i];
    float w00 = W1[0], w01 = W1[1], w10 = W1[2], w11 = W1[3];
    p1[i] = make_float2(di * (xv.x * w00 + xv.y * w10),
                        di * (xv.x * w01 + xv.y * w11));
}

__global__ void k_node_mid(const float* __restrict__ partial, int M,
                           const float* __restrict__ dinv, const float2* __restrict__ pin,
                           const float* __restrict__ b, const float* __restrict__ W,
                           float2* __restrict__ pout, int N) {
    int i = blockIdx.x * BLK + threadIdx.x;
    if (i >= N) return;
    int k = i >> BSHIFT, l = i & (BSIZE - 1);
    float2 self = pin[i];
    float ax = self.x, ay = self.y;
    for (int m = 0; m < M; ++m) {
        const float* pp = partial + ((size_t)(k * M + m)) * (BSIZE * 2) + 2 * l;
        ax += pp[0]; ay += pp[1];
    }
    float di = dinv[i];
    float h0 = fmaxf(fmaf(di, ax, b[0]), 0.f);
    float h1 = fmaxf(fmaf(di, ay, b[1]), 0.f);
    float w00 = W[0], w01 = W[1], w10 = W[2], w11 = W[3];
    pout[i] = make_float2(di * (h0 * w00 + h1 * w10),
                          di * (h0 * w01 + h1 * w11));
}

__global__ void k_out_init(float* __restrict__ out, const float* __restrict__ br, int G) {
    int i = blockIdx.x * BLK + threadIdx.x;
    if (i < G) out[i] = br[0];
}

__global__ void k_node_final(const float* __restrict__ partial, int M,
                             const float* __restrict__ dinv, const float2* __restrict__ pin,
                             const float* __restrict__ b, const float* __restrict__ Wr,
                             const int* __restrict__ batch, float* __restrict__ out, int N) {
    int i = blockIdx.x * BLK + threadIdx.x;
    bool valid = i < N;
    float s = 0.f;
    int key = -1;
    if (valid) {
        int k = i >> BSHIFT, l = i & (BSIZE - 1);
        float2 self = pin[i];
        float ax = self.x, ay = self.y;
        for (int m = 0; m < M; ++m) {
            const float* pp = partial + ((size_t)(k * M + m)) * (BSIZE * 2) + 2 * l;
            ax += pp[0]; ay += pp[1];
        }
        float di = dinv[i];
        float h0 = fmaxf(fmaf(di, ax, b[0]), 0.f);
        float h1 = fmaxf(fmaf(di, ay, b[1]), 0.f);
        s = fmaf(h0, Wr[0], h1 * Wr[1]);
        key = batch[i];
    }
    int lane = threadIdx.x & 63;
    for (int off = 1; off < 64; off <<= 1) {
        float s2 = __shfl_down(s, off);
        int k2 = __shfl_down(key, off);
        if (lane + off < 64 && k2 == key) s += s2;
    }
    int kprev = __shfl_up(key, 1);
    if (valid && (lane == 0 || kprev != key)) unsafeAtomicAdd(&out[key], s);
}

// ---------------- launch ----------------

extern "C" void kernel_launch(void* const* d_in, const int* in_sizes, int n_in,
                              void* d_out, int out_size, void* d_ws, size_t ws_size,
                              hipStream_t stream) {
    const float* x    = (const float*)d_in[0];
    const int*   ei   = (const int*)d_in[1];
    const int*   batch= (const int*)d_in[2];
    const float* W1   = (const float*)d_in[3];
    const float* b1   = (const float*)d_in[4];
    const float* W2   = (const float*)d_in[5];
    const float* b2   = (const float*)d_in[6];
    const float* W3   = (const float*)d_in[7];
    const float* b3   = (const float*)d_in[8];
    const float* Wr   = (const float*)d_in[9];
    const float* br   = (const float*)d_in[10];
    float* out = (float*)d_out;

    int N = in_sizes[0] / 2;
    int E = in_sizes[1] / 2;
    int G = out_size;
    const int* src = ei;
    const int* dst = ei + E;

    int K = (N + BSIZE - 1) >> BSHIFT;
    if (K > KPAD) return;
    int S = NSLICE;
    int chunk = (E + S - 1) / S;
    int NT2 = (N + TSIZE2 - 1) >> T2SHIFT;

    int sbits = 1;
    while ((1 << sbits) < N) ++sbits;
    if (sbits + BSHIFT > 32) return;
    int smask = (1 << sbits) - 1;

    auto pad16 = [](size_t b) { return (b + 15) & ~(size_t)15; };
    size_t fixed = pad16((size_t)E * 4)                       // packed
                 + pad16((size_t)S * K * 4)                   // hpart
                 + pad16((size_t)(K + 1) * 4)                 // basep
                 + pad16((size_t)K * 4)                       // totals
                 + pad16((size_t)N * 4)                       // dinv
                 + 2 * pad16((size_t)N * 8);                  // pA, pB
    size_t lvl2 = pad16((size_t)E * 4)                        // packed2
                + pad16((size_t)K * R2 * NT2 * 4)             // h2
                + pad16((size_t)K * (NT2 + 1) * 4);           // grpoff2

    bool sorted = (NT2 <= NT2MAX) && (NT2 * R2 <= SCAN2_T);
    int M = 16;
    for (;;) {
        size_t need = fixed + pad16((size_t)K * M * BSIZE * 2 * 4) + (sorted ? lvl2 : 0);
        if (need <= ws_size) break;
        if (M > 4) { M >>= 1; continue; }
        if (sorted) { sorted = false; M = 16; continue; }
        if (M > 1) { M >>= 1; continue; }
        return;
    }

    char* w = (char*)d_ws;
    size_t off = 0;
    auto carve = [&](size_t bytes) { void* p = w + off; off += (bytes + 15) & ~(size_t)15; return p; };
    int*    packed  = (int*)carve((size_t)E * 4);
    int*    hpart   = (int*)carve((size_t)S * K * 4);
    int*    basep   = (int*)carve((size_t)(K + 1) * 4);
    int*    totals  = (int*)carve((size_t)K * 4);
    float*  aggpart = (float*)carve((size_t)K * M * BSIZE * 2 * 4);
    float*  dinv    = (float*)carve((size_t)N * 4);
    float2* pA      = (float2*)carve((size_t)N * 8);
    float2* pB      = (float2*)carve((size_t)N * 8);
    int*    packed2 = nullptr;
    int*    h2      = nullptr;
    int*    grpoff2 = nullptr;
    if (sorted) {
        packed2 = (int*)carve((size_t)E * 4);
        h2      = (int*)carve((size_t)K * R2 * NT2 * 4);
        grpoff2 = (int*)carve((size_t)K * (NT2 + 1) * 4);
    }
    int* degpart = (int*)aggpart;            // reuse: consumed before first agg

    int NB = (N + BLK - 1) / BLK;
    int GB = (G + BLK - 1) / BLK;
    size_t smemK = (size_t)K * 4;
    int KM = K * M;

    // level-1 bucket build
    k_hist   <<<S, BLK, smemK, stream>>>(dst, hpart, E, chunk, K);
    k_colscan<<<K, NSLICE, 0, stream>>>(hpart, totals, K);
    k_base   <<<1, SCAN_T, 0, stream>>>(totals, basep, K);
    k_scatter<<<S, BLK, 0, stream>>>(src, dst, hpart, basep, packed, E, chunk, K, sbits);

    // degree -> dinv, p1
    k_deg   <<<KM, BLK, 0, stream>>>(packed, basep, M, degpart, sbits);
    k_node1 <<<NB, BLK, 0, stream>>>(degpart, M, x, W1, dinv, pA, N);

    if (sorted) {
        // level-2: sort each bucket by src tile
        k_hist2   <<<K * R2, BLK, 0, stream>>>(packed, basep, h2, NT2, smask);
        k_scan2   <<<K, SCAN2_T, 0, stream>>>(h2, basep, grpoff2, NT2);
        k_scatter2<<<K * R2, BLK, 0, stream>>>(packed, basep, h2, packed2, NT2, smask);

        k_agg2    <<<KM, BLK, 0, stream>>>(packed2, grpoff2, M, NT2, pA, aggpart, sbits, smask);
        k_node_mid<<<NB, BLK, 0, stream>>>(aggpart, M, dinv, pA, b1, W2, pB, N);
        k_agg2    <<<KM, BLK, 0, stream>>>(packed2, grpoff2, M, NT2, pB, aggpart, sbits, smask);
        k_node_mid<<<NB, BLK, 0, stream>>>(aggpart, M, dinv, pB, b2, W3, pA, N);
        k_agg2    <<<KM, BLK, 0, stream>>>(packed2, grpoff2, M, NT2, pA, aggpart, sbits, smask);
    } else {
        k_agg     <<<KM, BLK, 0, stream>>>(packed, basep, M, pA, aggpart, sbits, smask);
        k_node_mid<<<NB, BLK, 0, stream>>>(aggpart, M, dinv, pA, b1, W2, pB, N);
        k_agg     <<<KM, BLK, 0, stream>>>(packed, basep, M, pB, aggpart, sbits, smask);
        k_node_mid<<<NB, BLK, 0, stream>>>(aggpart, M, dinv, pB, b2, W3, pA, N);
        k_agg     <<<KM, BLK, 0, stream>>>(packed, basep, M, pA, aggpart, sbits, smask);
    }

    k_out_init<<<GB, BLK, 0, stream>>>(out, br, G);
    k_node_final<<<NB, BLK, 0, stream>>>(aggpart, M, dinv, pA, b3, Wr, batch, out, N);
}

// Round 12
// 593.792 us; speedup vs baseline: 1.1829x; 1.1829x over previous
//
#include <hip/hip_runtime.h>

#define BLK 256
#define BSHIFT 10
#define BSIZE 1024           // nodes per dst bucket (local index: 10 bits)
#define NSLICE 1024          // edge slices for hist/scatter
#define SCAN_T 512           // max K supported by single-block scan
#define KPAD 256             // max buckets (scan width in k_scatter)
#define EPT 8                // edges per thread per tile in k_scatter
#define TILE (BLK * EPT)     // 2048 edges staged per tile

typedef int iv4 __attribute__((ext_vector_type(4)));   // clang vector: nt-load legal

template <typename T>
__device__ __forceinline__ T ntload(const T* p) { return __builtin_nontemporal_load(p); }

__device__ __forceinline__ iv4 ntload4(const int* p) {
    return __builtin_nontemporal_load((const iv4*)p);
}

// ---------------- bucketed edge build (no global atomics) ----------------

__global__ void k_hist(const int* __restrict__ dst, int* __restrict__ partial,
                       int E, int chunk, int K) {
    extern __shared__ int cnt[];
    int s = blockIdx.x;
    for (int i = threadIdx.x; i < K; i += BLK) cnt[i] = 0;
    __syncthreads();
    int lo = s * chunk, hi = min(E, lo + chunk);
    for (int i = lo + threadIdx.x; i < hi; i += BLK)
        atomicAdd(&cnt[((unsigned)ntload(dst + i)) >> BSHIFT], 1);
    __syncthreads();
    int* prow = partial + (size_t)s * K;
    for (int i = threadIdx.x; i < K; i += BLK) prow[i] = cnt[i];
}

__global__ void __launch_bounds__(NSLICE) k_colscan(int* __restrict__ partial,
                                                    int* __restrict__ totals, int K) {
    __shared__ int sh[NSLICE];
    int k = blockIdx.x;
    int t = threadIdx.x;
    int v = partial[(size_t)t * K + k];
    sh[t] = v;
    __syncthreads();
    for (int off = 1; off < NSLICE; off <<= 1) {
        int u = (t >= off) ? sh[t - off] : 0;
        __syncthreads();
        sh[t] += u;
        __syncthreads();
    }
    partial[(size_t)t * K + k] = sh[t] - v;
    if (t == NSLICE - 1) totals[k] = sh[t];
}

__global__ void k_base(const int* __restrict__ totals, int* __restrict__ base, int K) {
    __shared__ int sh[SCAN_T];
    int t = threadIdx.x;
    int v = (t < K) ? totals[t] : 0;
    sh[t] = v;
    __syncthreads();
    for (int off = 1; off < SCAN_T; off <<= 1) {
        int u = (t >= off) ? sh[t - off] : 0;
        __syncthreads();
        sh[t] += u;
        __syncthreads();
    }
    if (t < K) base[t + 1] = sh[t];
    if (t == 0) base[0] = 0;
}

// tile counting-sort scatter: packed = (dst_local << sbits) | src
__global__ void __launch_bounds__(BLK) k_scatter(const int* __restrict__ src,
                                                 const int* __restrict__ dst,
                                                 const int* __restrict__ offs,
                                                 const int* __restrict__ base,
                                                 int* __restrict__ packed,
                                                 int E, int chunk, int K, int sbits) {
    __shared__ int cnt[KPAD];
    __shared__ int scn[KPAD];
    __shared__ int gstart[KPAD];
    __shared__ int cur[KPAD];
    __shared__ int stageval[TILE];
    __shared__ int stageaddr[TILE];
    int s = blockIdx.x;
    int tid = threadIdx.x;
    const int* orow = offs + (size_t)s * K;
    if (tid < K) cur[tid] = orow[tid] + base[tid];
    int lo = s * chunk, hi = min(E, lo + chunk);

    for (int tlo = lo; tlo < hi; tlo += TILE) {
        for (int k2 = tid; k2 < KPAD; k2 += BLK) cnt[k2] = 0;
        __syncthreads();

        int kk[EPT], rr[EPT], vv[EPT];
#pragma unroll
        for (int j = 0; j < EPT; ++j) {
            int i = tlo + j * BLK + tid;
            kk[j] = -1;
            if (i < hi) {
                int d = ntload(dst + i);
                int sc = ntload(src + i);
                kk[j] = ((unsigned)d) >> BSHIFT;
                vv[j] = ((d & (BSIZE - 1)) << sbits) | sc;
                rr[j] = atomicAdd(&cnt[kk[j]], 1);
            }
        }
        __syncthreads();

        int c = cnt[tid];
        scn[tid] = c;
        __syncthreads();
        for (int off = 1; off < KPAD; off <<= 1) {
            int u = (tid >= off) ? scn[tid - off] : 0;
            __syncthreads();
            scn[tid] += u;
            __syncthreads();
        }
        scn[tid] -= c;
        gstart[tid] = cur[tid];
        cur[tid] += c;
        __syncthreads();

#pragma unroll
        for (int j = 0; j < EPT; ++j) {
            if (kk[j] >= 0) {
                int idx = scn[kk[j]] + rr[j];
                stageval[idx]  = vv[j];
                stageaddr[idx] = gstart[kk[j]] + rr[j];
            }
        }
        __syncthreads();

        int tot = min(hi - tlo, TILE);
        for (int i2 = tid; i2 < tot; i2 += BLK)
            packed[stageaddr[i2]] = stageval[i2];
        __syncthreads();
    }
}

// ---------------- aggregation passes (grid = K*M, private LDS tiles) -------

// degree counts -> degpart[b][BSIZE]
__global__ void k_deg(const int* __restrict__ packed, const int* __restrict__ base,
                      int M, int* __restrict__ degpart, int sbits) {
    __shared__ int cnt[BSIZE];
    int b = blockIdx.x;
    int k = b / M, m = b - k * M;
    for (int i = threadIdx.x; i < BSIZE; i += BLK) cnt[i] = 0;
    __syncthreads();
    int lo = base[k], len = base[k + 1] - lo;
    int l0 = lo + (int)(((long long)len * m) / M);
    int l1 = lo + (int)(((long long)len * (m + 1)) / M);
    int a0 = min((l0 + 3) & ~3, l1);
    int a1 = max(l1 & ~3, a0);
    for (int i = l0 + threadIdx.x; i < a0; i += BLK)
        atomicAdd(&cnt[((unsigned)ntload(packed + i)) >> sbits], 1);
    for (int i = a0 + 4 * threadIdx.x; i < a1; i += 4 * BLK) {
        iv4 q = ntload4(packed + i);
        atomicAdd(&cnt[((unsigned)q.x) >> sbits], 1);
        atomicAdd(&cnt[((unsigned)q.y) >> sbits], 1);
        atomicAdd(&cnt[((unsigned)q.z) >> sbits], 1);
        atomicAdd(&cnt[((unsigned)q.w) >> sbits], 1);
    }
    for (int i = a1 + threadIdx.x; i < l1; i += BLK)
        atomicAdd(&cnt[((unsigned)ntload(packed + i)) >> sbits], 1);
    __syncthreads();
    int* outp = degpart + (size_t)b * BSIZE;
    for (int i = threadIdx.x; i < BSIZE; i += BLK) outp[i] = cnt[i];
}

// sum p[src] into private LDS tile -> partial[b][BSIZE][2]
// 16 edges/thread/iter: 16 independent gathers in flight (latency hiding via MLP)
__global__ void __launch_bounds__(BLK) k_agg(const int* __restrict__ packed,
                                             const int* __restrict__ base,
                                             int M, const float2* __restrict__ pin,
                                             float* __restrict__ partial,
                                             int sbits, int smask) {
    __shared__ float accx[BSIZE];
    __shared__ float accy[BSIZE];
    int b = blockIdx.x;
    int k = b / M, m = b - k * M;
    for (int i = threadIdx.x; i < BSIZE; i += BLK) { accx[i] = 0.f; accy[i] = 0.f; }
    __syncthreads();
    int lo = base[k], len = base[k + 1] - lo;
    int l0 = lo + (int)(((long long)len * m) / M);
    int l1 = lo + (int)(((long long)len * (m + 1)) / M);
    int a0 = min((l0 + 3) & ~3, l1);
    int a1 = a0 + (((l1 - a0) / (16 * BLK)) * (16 * BLK));   // 16-wide body coverage

    for (int i = a0 + 16 * threadIdx.x; i < a1; i += 16 * BLK) {
        iv4 q0 = ntload4(packed + i);
        iv4 q1 = ntload4(packed + i + 4);
        iv4 q2 = ntload4(packed + i + 8);
        iv4 q3 = ntload4(packed + i + 12);
        unsigned v[16];
        v[0]=q0.x; v[1]=q0.y; v[2]=q0.z; v[3]=q0.w;
        v[4]=q1.x; v[5]=q1.y; v[6]=q1.z; v[7]=q1.w;
        v[8]=q2.x; v[9]=q2.y; v[10]=q2.z; v[11]=q2.w;
        v[12]=q3.x; v[13]=q3.y; v[14]=q3.z; v[15]=q3.w;
        float2 e[16];
#pragma unroll
        for (int j = 0; j < 16; ++j) e[j] = pin[v[j] & smask];   // 16 gathers in flight
#pragma unroll
        for (int j = 0; j < 16; ++j) {
            int l = v[j] >> sbits;
            atomicAdd(&accx[l], e[j].x);
            atomicAdd(&accy[l], e[j].y);
        }
    }
    // remainder: 4-wide then scalar
    int a2 = a1 + (((l1 - a1) / (4 * BLK)) * (4 * BLK));
    for (int i = a1 + 4 * threadIdx.x; i < a2; i += 4 * BLK) {
        iv4 q = ntload4(packed + i);
        unsigned v0 = q.x, v1 = q.y, v2 = q.z, v3 = q.w;
        float2 e0 = pin[v0 & smask];
        float2 e1 = pin[v1 & smask];
        float2 e2 = pin[v2 & smask];
        float2 e3 = pin[v3 & smask];
        int l0i = v0 >> sbits, l1i = v1 >> sbits, l2i = v2 >> sbits, l3i = v3 >> sbits;
        atomicAdd(&accx[l0i], e0.x); atomicAdd(&accy[l0i], e0.y);
        atomicAdd(&accx[l1i], e1.x); atomicAdd(&accy[l1i], e1.y);
        atomicAdd(&accx[l2i], e2.x); atomicAdd(&accy[l2i], e2.y);
        atomicAdd(&accx[l3i], e3.x); atomicAdd(&accy[l3i], e3.y);
    }
    for (int j = a2 + threadIdx.x; j < l1; j += BLK) {
        unsigned v = (unsigned)ntload(packed + j);
        float2 pv = pin[v & smask];
        int l = v >> sbits;
        atomicAdd(&accx[l], pv.x);
        atomicAdd(&accy[l], pv.y);
    }
    // head [l0, a0)
    for (int j = l0 + threadIdx.x; j < a0; j += BLK) {
        unsigned v = (unsigned)ntload(packed + j);
        float2 pv = pin[v & smask];
        int l = v >> sbits;
        atomicAdd(&accx[l], pv.x);
        atomicAdd(&accy[l], pv.y);
    }
    __syncthreads();
    float* outp = partial + (size_t)b * (BSIZE * 2);
    for (int j = threadIdx.x * 2; j < BSIZE; j += BLK * 2) {
        float4 o = make_float4(accx[j], accy[j], accx[j + 1], accy[j + 1]);
        *(float4*)(outp + 2 * j) = o;
    }
}

// ---------------- node epilogues ----------------

__global__ void k_node1(const int* __restrict__ degpart, int M,
                        const float* __restrict__ x, const float* __restrict__ W1,
                        float* __restrict__ dinv, float2* __restrict__ p1, int N) {
    int i = blockIdx.x * BLK + threadIdx.x;
    if (i >= N) return;
    int k = i >> BSHIFT, l = i & (BSIZE - 1);
    int c = 0;
    for (int m = 0; m < M; ++m) c += degpart[((size_t)(k * M + m)) * BSIZE + l];
    float di = rsqrtf((float)c + 1.0f);
    dinv[i] = di;
    float2 xv = ((const float2*)x)[i];
    float w00 = W1[0], w01 = W1[1], w10 = W1[2], w11 = W1[3];
    p1[i] = make_float2(di * (xv.x * w00 + xv.y * w10),
                        di * (xv.x * w01 + xv.y * w11));
}

__global__ void k_node_mid(const float* __restrict__ partial, int M,
                           const float* __restrict__ dinv, const float2* __restrict__ pin,
                           const float* __restrict__ b, const float* __restrict__ W,
                           float2* __restrict__ pout, int N) {
    int i = blockIdx.x * BLK + threadIdx.x;
    if (i >= N) return;
    int k = i >> BSHIFT, l = i & (BSIZE - 1);
    float2 self = pin[i];
    float ax = self.x, ay = self.y;
    for (int m = 0; m < M; ++m) {
        const float* pp = partial + ((size_t)(k * M + m)) * (BSIZE * 2) + 2 * l;
        ax += pp[0]; ay += pp[1];
    }
    float di = dinv[i];
    float h0 = fmaxf(fmaf(di, ax, b[0]), 0.f);
    float h1 = fmaxf(fmaf(di, ay, b[1]), 0.f);
    float w00 = W[0], w01 = W[1], w10 = W[2], w11 = W[3];
    pout[i] = make_float2(di * (h0 * w00 + h1 * w10),
                          di * (h0 * w01 + h1 * w11));
}

__global__ void k_out_init(float* __restrict__ out, const float* __restrict__ br, int G) {
    int i = blockIdx.x * BLK + threadIdx.x;
    if (i < G) out[i] = br[0];
}

__global__ void k_node_final(const float* __restrict__ partial, int M,
                             const float* __restrict__ dinv, const float2* __restrict__ pin,
                             const float* __restrict__ b, const float* __restrict__ Wr,
                             const int* __restrict__ batch, float* __restrict__ out, int N) {
    int i = blockIdx.x * BLK + threadIdx.x;
    bool valid = i < N;
    float s = 0.f;
    int key = -1;
    if (valid) {
        int k = i >> BSHIFT, l = i & (BSIZE - 1);
        float2 self = pin[i];
        float ax = self.x, ay = self.y;
        for (int m = 0; m < M; ++m) {
            const float* pp = partial + ((size_t)(k * M + m)) * (BSIZE * 2) + 2 * l;
            ax += pp[0]; ay += pp[1];
        }
        float di = dinv[i];
        float h0 = fmaxf(fmaf(di, ax, b[0]), 0.f);
        float h1 = fmaxf(fmaf(di, ay, b[1]), 0.f);
        s = fmaf(h0, Wr[0], h1 * Wr[1]);
        key = batch[i];
    }
    int lane = threadIdx.x & 63;
    for (int off = 1; off < 64; off <<= 1) {
        float s2 = __shfl_down(s, off);
        int k2 = __shfl_down(key, off);
        if (lane + off < 64 && k2 == key) s += s2;
    }
    int kprev = __shfl_up(key, 1);
    if (valid && (lane == 0 || kprev != key)) unsafeAtomicAdd(&out[key], s);
}

// ---------------- launch ----------------

extern "C" void kernel_launch(void* const* d_in, const int* in_sizes, int n_in,
                              void* d_out, int out_size, void* d_ws, size_t ws_size,
                              hipStream_t stream) {
    const float* x    = (const float*)d_in[0];
    const int*   ei   = (const int*)d_in[1];
    const int*   batch= (const int*)d_in[2];
    const float* W1   = (const float*)d_in[3];
    const float* b1   = (const float*)d_in[4];
    const float* W2   = (const float*)d_in[5];
    const float* b2   = (const float*)d_in[6];
    const float* W3   = (const float*)d_in[7];
    const float* b3   = (const float*)d_in[8];
    const float* Wr   = (const float*)d_in[9];
    const float* br   = (const float*)d_in[10];
    float* out = (float*)d_out;

    int N = in_sizes[0] / 2;
    int E = in_sizes[1] / 2;
    int G = out_size;
    const int* src = ei;
    const int* dst = ei + E;

    int K = (N + BSIZE - 1) >> BSHIFT;
    if (K > KPAD) return;
    int S = NSLICE;
    int chunk = (E + S - 1) / S;

    int sbits = 1;
    while ((1 << sbits) < N) ++sbits;
    if (sbits + BSHIFT > 32) return;
    int smask = (1 << sbits) - 1;

    // pick M (sub-blocks per bucket) to fit workspace
    int M = 16;
    size_t need;
    for (;;) {
        need = (((size_t)E * 4 + 15) & ~(size_t)15)
             + (((size_t)S * K * 4 + 15) & ~(size_t)15)
             + (((size_t)(K + 1) * 4 + 15) & ~(size_t)15)
             + (((size_t)K * 4 + 15) & ~(size_t)15)
             + (((size_t)K * M * BSIZE * 2 * 4 + 15) & ~(size_t)15)
             + (((size_t)N * 4 + 15) & ~(size_t)15)
             + 2 * (((size_t)N * 8 + 15) & ~(size_t)15);
        if (need <= ws_size || M == 1) break;
        M >>= 1;
    }
    if (need > ws_size) return;

    char* w = (char*)d_ws;
    size_t off = 0;
    auto carve = [&](size_t bytes) { void* p = w + off; off += (bytes + 15) & ~(size_t)15; return p; };
    int*    packed  = (int*)carve((size_t)E * 4);
    int*    hpart   = (int*)carve((size_t)S * K * 4);
    int*    basep   = (int*)carve((size_t)(K + 1) * 4);
    int*    totals  = (int*)carve((size_t)K * 4);
    float*  aggpart = (float*)carve((size_t)K * M * BSIZE * 2 * 4);
    float*  dinv    = (float*)carve((size_t)N * 4);
    float2* pA      = (float2*)carve((size_t)N * 8);
    float2* pB      = (float2*)carve((size_t)N * 8);
    int*    degpart = (int*)aggpart;            // reuse: consumed before first k_agg

    int NB = (N + BLK - 1) / BLK;
    int GB = (G + BLK - 1) / BLK;
    size_t smemK = (size_t)K * 4;
    int KM = K * M;

    // build bucketed edge list
    k_hist   <<<S, BLK, smemK, stream>>>(dst, hpart, E, chunk, K);
    k_colscan<<<K, NSLICE, 0, stream>>>(hpart, totals, K);
    k_base   <<<1, SCAN_T, 0, stream>>>(totals, basep, K);
    k_scatter<<<S, BLK, 0, stream>>>(src, dst, hpart, basep, packed, E, chunk, K, sbits);

    // degree -> dinv, p1
    k_deg   <<<KM, BLK, 0, stream>>>(packed, basep, M, degpart, sbits);
    k_node1 <<<NB, BLK, 0, stream>>>(degpart, M, x, W1, dinv, pA, N);

    // layer 1
    k_agg     <<<KM, BLK, 0, stream>>>(packed, basep, M, pA, aggpart, sbits, smask);
    k_node_mid<<<NB, BLK, 0, stream>>>(aggpart, M, dinv, pA, b1, W2, pB, N);
    // layer 2
    k_agg     <<<KM, BLK, 0, stream>>>(packed, basep, M, pB, aggpart, sbits, smask);
    k_node_mid<<<NB, BLK, 0, stream>>>(aggpart, M, dinv, pB, b2, W3, pA, N);
    // layer 3 + pool
    k_agg     <<<KM, BLK, 0, stream>>>(packed, basep, M, pA, aggpart, sbits, smask);
    k_out_init<<<GB, BLK, 0, stream>>>(out, br, G);
    k_node_final<<<NB, BLK, 0, stream>>>(aggpart, M, dinv, pA, b3, Wr, batch, out, N);
}

// Round 13
// 592.480 us; speedup vs baseline: 1.1856x; 1.0022x over previous
//
#include <hip/hip_runtime.h>

#define BLK 256
#define BSHIFT 10
#define BSIZE 1024           // nodes per dst bucket (local index: 10 bits)
#define NSLICE 1024          // edge slices for hist/scatter
#define SCAN_T 512           // max K supported by single-block scan
#define KPAD 256             // max buckets (scan width in k_scatter)
#define EPT 8                // edges per thread per tile in scatter kernels
#define TILE (BLK * EPT)     // 2048 edges staged per tile
#define R2 8                 // sub-slices per bucket in within-bucket sort

typedef int iv4 __attribute__((ext_vector_type(4)));   // clang vector: nt-load legal

template <typename T>
__device__ __forceinline__ T ntload(const T* p) { return __builtin_nontemporal_load(p); }

__device__ __forceinline__ iv4 ntload4(const int* p) {
    return __builtin_nontemporal_load((const iv4*)p);
}

// ---------------- level-1: bucket by dst>>10 (no global atomics) ------------

__global__ void k_hist(const int* __restrict__ dst, int* __restrict__ partial,
                       int E, int chunk, int K) {
    extern __shared__ int cnt[];
    int s = blockIdx.x;
    for (int i = threadIdx.x; i < K; i += BLK) cnt[i] = 0;
    __syncthreads();
    int lo = s * chunk, hi = min(E, lo + chunk);
    for (int i = lo + threadIdx.x; i < hi; i += BLK)
        atomicAdd(&cnt[((unsigned)ntload(dst + i)) >> BSHIFT], 1);
    __syncthreads();
    int* prow = partial + (size_t)s * K;
    for (int i = threadIdx.x; i < K; i += BLK) prow[i] = cnt[i];
}

__global__ void __launch_bounds__(NSLICE) k_colscan(int* __restrict__ partial,
                                                    int* __restrict__ totals, int K) {
    __shared__ int sh[NSLICE];
    int k = blockIdx.x;
    int t = threadIdx.x;
    int v = partial[(size_t)t * K + k];
    sh[t] = v;
    __syncthreads();
    for (int off = 1; off < NSLICE; off <<= 1) {
        int u = (t >= off) ? sh[t - off] : 0;
        __syncthreads();
        sh[t] += u;
        __syncthreads();
    }
    partial[(size_t)t * K + k] = sh[t] - v;
    if (t == NSLICE - 1) totals[k] = sh[t];
}

__global__ void k_base(const int* __restrict__ totals, int* __restrict__ base, int K) {
    __shared__ int sh[SCAN_T];
    int t = threadIdx.x;
    int v = (t < K) ? totals[t] : 0;
    sh[t] = v;
    __syncthreads();
    for (int off = 1; off < SCAN_T; off <<= 1) {
        int u = (t >= off) ? sh[t - off] : 0;
        __syncthreads();
        sh[t] += u;
        __syncthreads();
    }
    if (t < K) base[t + 1] = sh[t];
    if (t == 0) base[0] = 0;
}

// tile counting-sort scatter: packed = (dst_local << sbits) | src
__global__ void __launch_bounds__(BLK) k_scatter(const int* __restrict__ src,
                                                 const int* __restrict__ dst,
                                                 const int* __restrict__ offs,
                                                 const int* __restrict__ base,
                                                 int* __restrict__ packed,
                                                 int E, int chunk, int K, int sbits) {
    __shared__ int cnt[KPAD];
    __shared__ int scn[KPAD];
    __shared__ int gstart[KPAD];
    __shared__ int cur[KPAD];
    __shared__ int stageval[TILE];
    __shared__ int stageaddr[TILE];
    int s = blockIdx.x;
    int tid = threadIdx.x;
    const int* orow = offs + (size_t)s * K;
    if (tid < K) cur[tid] = orow[tid] + base[tid];
    int lo = s * chunk, hi = min(E, lo + chunk);

    for (int tlo = lo; tlo < hi; tlo += TILE) {
        for (int k2 = tid; k2 < KPAD; k2 += BLK) cnt[k2] = 0;
        __syncthreads();

        int kk[EPT], rr[EPT], vv[EPT];
#pragma unroll
        for (int j = 0; j < EPT; ++j) {
            int i = tlo + j * BLK + tid;
            kk[j] = -1;
            if (i < hi) {
                int d = ntload(dst + i);
                int sc = ntload(src + i);
                kk[j] = ((unsigned)d) >> BSHIFT;
                vv[j] = ((d & (BSIZE - 1)) << sbits) | sc;
                rr[j] = atomicAdd(&cnt[kk[j]], 1);
            }
        }
        __syncthreads();

        int c = cnt[tid];
        scn[tid] = c;
        __syncthreads();
        for (int off = 1; off < KPAD; off <<= 1) {
            int u = (tid >= off) ? scn[tid - off] : 0;
            __syncthreads();
            scn[tid] += u;
            __syncthreads();
        }
        scn[tid] -= c;
        gstart[tid] = cur[tid];
        cur[tid] += c;
        __syncthreads();

#pragma unroll
        for (int j = 0; j < EPT; ++j) {
            if (kk[j] >= 0) {
                int idx = scn[kk[j]] + rr[j];
                stageval[idx]  = vv[j];
                stageaddr[idx] = gstart[kk[j]] + rr[j];
            }
        }
        __syncthreads();

        int tot = min(hi - tlo, TILE);
        for (int i2 = tid; i2 < tot; i2 += BLK)
            packed[stageaddr[i2]] = stageval[i2];
        __syncthreads();
    }
}

// ---------------- level-2: full sort within bucket by dst_local -------------

// per (bucket, slice) histogram of dst_local -> h2[b][BSIZE]
__global__ void __launch_bounds__(BLK) k_hist2(const int* __restrict__ packed,
                                               const int* __restrict__ base,
                                               int* __restrict__ h2, int sbits) {
    __shared__ int cnt[BSIZE];
    int b = blockIdx.x;              // k*R2 + r
    int k = b / R2, r = b - k * R2;
    for (int i = threadIdx.x; i < BSIZE; i += BLK) cnt[i] = 0;
    __syncthreads();
    int lo = base[k], len = base[k + 1] - lo;
    int s0 = lo + (int)(((long long)len * r) / R2);
    int s1 = lo + (int)(((long long)len * (r + 1)) / R2);
    for (int i = s0 + threadIdx.x; i < s1; i += BLK)
        atomicAdd(&cnt[((unsigned)ntload(packed + i)) >> sbits], 1);
    __syncthreads();
    int* hrow = h2 + (size_t)b * BSIZE;
    for (int i = threadIdx.x; i < BSIZE; i += BLK) hrow[i] = cnt[i];
}

// per-bucket scan (bin-major, slice-minor): h2 -> absolute write offsets
__global__ void __launch_bounds__(BSIZE) k_scan2(int* __restrict__ h2,
                                                 const int* __restrict__ base) {
    __shared__ int sh[BSIZE];
    int k = blockIdx.x;
    int t = threadIdx.x;             // bin
    int vals[R2];
    int tot = 0;
#pragma unroll
    for (int r = 0; r < R2; ++r) {
        vals[r] = h2[((size_t)(k * R2 + r)) * BSIZE + t];
        tot += vals[r];
    }
    sh[t] = tot;
    __syncthreads();
    for (int off = 1; off < BSIZE; off <<= 1) {
        int u = (t >= off) ? sh[t - off] : 0;
        __syncthreads();
        sh[t] += u;
        __syncthreads();
    }
    int run = base[k] + sh[t] - tot;
#pragma unroll
    for (int r = 0; r < R2; ++r) {
        int c = vals[r];
        h2[((size_t)(k * R2 + r)) * BSIZE + t] = run;
        run += c;
    }
}

// counting-sort each (bucket, slice) by dst_local; burst-flush coalesced
__global__ void __launch_bounds__(BLK) k_scatter3(const int* __restrict__ packed,
                                                  const int* __restrict__ base,
                                                  const int* __restrict__ h2,
                                                  int* __restrict__ packed2, int sbits) {
    __shared__ int cnt[BSIZE];       // counts -> exclusive offsets (in place)
    __shared__ int cur[BSIZE];
    __shared__ int gstart[BSIZE];
    __shared__ int tsum[BLK];
    __shared__ int sval[TILE];
    __shared__ int sadr[TILE];
    int b = blockIdx.x;              // k*R2 + r
    int k = b / R2, r = b - k * R2;
    int tid = threadIdx.x;
    const int* hrow = h2 + (size_t)b * BSIZE;
    for (int i = tid; i < BSIZE; i += BLK) cur[i] = hrow[i];
    int lo = base[k], len = base[k + 1] - lo;
    int s0 = lo + (int)(((long long)len * r) / R2);
    int s1 = lo + (int)(((long long)len * (r + 1)) / R2);

    for (int tlo = s0; tlo < s1; tlo += TILE) {
        for (int i = tid; i < BSIZE; i += BLK) cnt[i] = 0;
        __syncthreads();

        int kk[EPT], rr[EPT], vv[EPT];
#pragma unroll
        for (int j = 0; j < EPT; ++j) {
            int i = tlo + j * BLK + tid;
            kk[j] = -1;
            if (i < s1) {
                int v = ntload(packed + i);
                vv[j] = v;
                kk[j] = ((unsigned)v) >> sbits;
                rr[j] = atomicAdd(&cnt[kk[j]], 1);
            }
        }
        __syncthreads();

        // scan over 1024 bins: 4 bins/thread + 256-wide block scan
        int c0 = cnt[4 * tid], c1 = cnt[4 * tid + 1],
            c2 = cnt[4 * tid + 2], c3 = cnt[4 * tid + 3];
        int sum = c0 + c1 + c2 + c3;
        tsum[tid] = sum;
        __syncthreads();
        for (int off = 1; off < BLK; off <<= 1) {
            int u = (tid >= off) ? tsum[tid - off] : 0;
            __syncthreads();
            tsum[tid] += u;
            __syncthreads();
        }
        int runb = tsum[tid] - sum;  // exclusive
        gstart[4 * tid]     = cur[4 * tid];     cur[4 * tid]     += c0;
        gstart[4 * tid + 1] = cur[4 * tid + 1]; cur[4 * tid + 1] += c1;
        gstart[4 * tid + 2] = cur[4 * tid + 2]; cur[4 * tid + 2] += c2;
        gstart[4 * tid + 3] = cur[4 * tid + 3]; cur[4 * tid + 3] += c3;
        cnt[4 * tid]     = runb;
        cnt[4 * tid + 1] = runb + c0;
        cnt[4 * tid + 2] = runb + c0 + c1;
        cnt[4 * tid + 3] = runb + c0 + c1 + c2;
        __syncthreads();

#pragma unroll
        for (int j = 0; j < EPT; ++j) {
            if (kk[j] >= 0) {
                int idx = cnt[kk[j]] + rr[j];
                sval[idx] = vv[j];
                sadr[idx] = gstart[kk[j]] + rr[j];
            }
        }
        __syncthreads();

        int tot = min(s1 - tlo, TILE);
        for (int i2 = tid; i2 < tot; i2 += BLK)
            packed2[sadr[i2]] = sval[i2];
        __syncthreads();
    }
}

// ---------------- aggregation ----------------

// degree counts -> degpart[b][BSIZE]  (order-independent; reads level-1 packed)
__global__ void k_deg(const int* __restrict__ packed, const int* __restrict__ base,
                      int M, int* __restrict__ degpart, int sbits) {
    __shared__ int cnt[BSIZE];
    int b = blockIdx.x;
    int k = b / M, m = b - k * M;
    for (int i = threadIdx.x; i < BSIZE; i += BLK) cnt[i] = 0;
    __syncthreads();
    int lo = base[k], len = base[k + 1] - lo;
    int l0 = lo + (int)(((long long)len * m) / M);
    int l1 = lo + (int)(((long long)len * (m + 1)) / M);
    int a0 = min((l0 + 3) & ~3, l1);
    int a1 = max(l1 & ~3, a0);
    for (int i = l0 + threadIdx.x; i < a0; i += BLK)
        atomicAdd(&cnt[((unsigned)ntload(packed + i)) >> sbits], 1);
    for (int i = a0 + 4 * threadIdx.x; i < a1; i += 4 * BLK) {
        iv4 q = ntload4(packed + i);
        atomicAdd(&cnt[((unsigned)q.x) >> sbits], 1);
        atomicAdd(&cnt[((unsigned)q.y) >> sbits], 1);
        atomicAdd(&cnt[((unsigned)q.z) >> sbits], 1);
        atomicAdd(&cnt[((unsigned)q.w) >> sbits], 1);
    }
    for (int i = a1 + threadIdx.x; i < l1; i += BLK)
        atomicAdd(&cnt[((unsigned)ntload(packed + i)) >> sbits], 1);
    __syncthreads();
    int* outp = degpart + (size_t)b * BSIZE;
    for (int i = threadIdx.x; i < BSIZE; i += BLK) outp[i] = cnt[i];
}

// sorted-edge agg: 64-edge windows, segmented shfl suffix-reduce, atomics only at heads
__global__ void __launch_bounds__(BLK) k_agg3(const int* __restrict__ packed2,
                                              const int* __restrict__ base,
                                              int M, const float2* __restrict__ pin,
                                              float* __restrict__ partial,
                                              int sbits, int smask) {
    __shared__ float accx[BSIZE];
    __shared__ float accy[BSIZE];
    int b = blockIdx.x;
    int k = b / M, m = b - k * M;
    for (int i = threadIdx.x; i < BSIZE; i += BLK) { accx[i] = 0.f; accy[i] = 0.f; }
    __syncthreads();
    int lo = base[k], len = base[k + 1] - lo;
    int l0 = lo + (int)(((long long)len * m) / M);
    int l1 = lo + (int)(((long long)len * (m + 1)) / M);
    int lane = threadIdx.x & 63;
    int wid = threadIdx.x >> 6;              // 4 waves per block

    for (int wbase = l0 + wid * 64; wbase < l1; wbase += 4 * 64) {
        int i = wbase + lane;
        bool valid = i < l1;
        unsigned v = valid ? (unsigned)ntload(packed2 + i) : 0u;
        int key = valid ? (int)(v >> sbits) : -1;
        float sx = 0.f, sy = 0.f;
        if (valid) {
            float2 e = pin[v & smask];       // the one random gather
            sx = e.x; sy = e.y;
        }
        // segmented suffix sum over sorted keys
        for (int off = 1; off < 64; off <<= 1) {
            float x2 = __shfl_down(sx, off);
            float y2 = __shfl_down(sy, off);
            int  k2 = __shfl_down(key, off);
            if (lane + off < 64 && k2 == key) { sx += x2; sy += y2; }
        }
        int kprev = __shfl_up(key, 1);
        if (valid && (lane == 0 || kprev != key)) {
            atomicAdd(&accx[key], sx);
            atomicAdd(&accy[key], sy);
        }
    }
    __syncthreads();
    float* outp = partial + (size_t)b * (BSIZE * 2);
    for (int j = threadIdx.x * 2; j < BSIZE; j += BLK * 2) {
        float4 o = make_float4(accx[j], accy[j], accx[j + 1], accy[j + 1]);
        *(float4*)(outp + 2 * j) = o;
    }
}

// fallback: unsorted gather agg (4-wide) when ws too small for level-2
__global__ void __launch_bounds__(BLK) k_agg(const int* __restrict__ packed,
                                             const int* __restrict__ base,
                                             int M, const float2* __restrict__ pin,
                                             float* __restrict__ partial,
                                             int sbits, int smask) {
    __shared__ float accx[BSIZE];
    __shared__ float accy[BSIZE];
    int b = blockIdx.x;
    int k = b / M, m = b - k * M;
    for (int i = threadIdx.x; i < BSIZE; i += BLK) { accx[i] = 0.f; accy[i] = 0.f; }
    __syncthreads();
    int lo = base[k], len = base[k + 1] - lo;
    int l0 = lo + (int)(((long long)len * m) / M);
    int l1 = lo + (int)(((long long)len * (m + 1)) / M);
    int a0 = min((l0 + 3) & ~3, l1);
    int a1 = max(l1 & ~3, a0);
    for (int i = l0 + threadIdx.x; i < a0; i += BLK) {
        unsigned v = (unsigned)ntload(packed + i);
        float2 pv = pin[v & smask];
        int l = v >> sbits;
        atomicAdd(&accx[l], pv.x);
        atomicAdd(&accy[l], pv.y);
    }
    for (int i = a0 + 4 * threadIdx.x; i < a1; i += 4 * BLK) {
        iv4 q = ntload4(packed + i);
        unsigned v0 = q.x, v1 = q.y, v2 = q.z, v3 = q.w;
        float2 e0 = pin[v0 & smask];
        float2 e1 = pin[v1 & smask];
        float2 e2 = pin[v2 & smask];
        float2 e3 = pin[v3 & smask];
        int l0i = v0 >> sbits, l1i = v1 >> sbits, l2i = v2 >> sbits, l3i = v3 >> sbits;
        atomicAdd(&accx[l0i], e0.x); atomicAdd(&accy[l0i], e0.y);
        atomicAdd(&accx[l1i], e1.x); atomicAdd(&accy[l1i], e1.y);
        atomicAdd(&accx[l2i], e2.x); atomicAdd(&accy[l2i], e2.y);
        atomicAdd(&accx[l3i], e3.x); atomicAdd(&accy[l3i], e3.y);
    }
    for (int j = a1 + threadIdx.x; j < l1; j += BLK) {
        unsigned v = (unsigned)ntload(packed + j);
        float2 pv = pin[v & smask];
        int l = v >> sbits;
        atomicAdd(&accx[l], pv.x);
        atomicAdd(&accy[l], pv.y);
    }
    __syncthreads();
    float* outp = partial + (size_t)b * (BSIZE * 2);
    for (int j = threadIdx.x * 2; j < BSIZE; j += BLK * 2) {
        float4 o = make_float4(accx[j], accy[j], accx[j + 1], accy[j + 1]);
        *(float4*)(outp + 2 * j) = o;
    }
}

// ---------------- node epilogues ----------------

__global__ void k_node1(const int* __restrict__ degpart, int M,
                        const float* __restrict__ x, const float* __restrict__ W1,
                        float* __restrict__ dinv, float2* __restrict__ p1, int N) {
    int i = blockIdx.x * BLK + threadIdx.x;
    if (i >= N) return;
    int k = i >> BSHIFT, l = i & (BSIZE - 1);
    int c = 0;
    for (int m = 0; m < M; ++m) c += degpart[((size_t)(k * M + m)) * BSIZE + l];
    float di = rsqrtf((float)c + 1.0f);
    dinv[i] = di;
    float2 xv = ((const float2*)x)[i];
    float w00 = W1[0], w01 = W1[1], w10 = W1[2], w11 = W1[3];
    p1[i] = make_float2(di * (xv.x * w00 + xv.y * w10),
                        di * (xv.x * w01 + xv.y * w11));
}

__global__ void k_node_mid(const float* __restrict__ partial, int M,
                           const float* __restrict__ dinv, const float2* __restrict__ pin,
                           const float* __restrict__ b, const float* __restrict__ W,
                           float2* __restrict__ pout, int N) {
    int i = blockIdx.x * BLK + threadIdx.x;
    if (i >= N) return;
    int k = i >> BSHIFT, l = i & (BSIZE - 1);
    float2 self = pin[i];
    float ax = self.x, ay = self.y;
    for (int m = 0; m < M; ++m) {
        const float* pp = partial + ((size_t)(k * M + m)) * (BSIZE * 2) + 2 * l;
        ax += pp[0]; ay += pp[1];
    }
    float di = dinv[i];
    float h0 = fmaxf(fmaf(di, ax, b[0]), 0.f);
    float h1 = fmaxf(fmaf(di, ay, b[1]), 0.f);
    float w00 = W[0], w01 = W[1], w10 = W[2], w11 = W[3];
    pout[i] = make_float2(di * (h0 * w00 + h1 * w10),
                          di * (h0 * w01 + h1 * w11));
}

__global__ void k_out_init(float* __restrict__ out, const float* __restrict__ br, int G) {
    int i = blockIdx.x * BLK + threadIdx.x;
    if (i < G) out[i] = br[0];
}

__global__ void k_node_final(const float* __restrict__ partial, int M,
                             const float* __restrict__ dinv, const float2* __restrict__ pin,
                             const float* __restrict__ b, const float* __restrict__ Wr,
                             const int* __restrict__ batch, float* __restrict__ out, int N) {
    int i = blockIdx.x * BLK + threadIdx.x;
    bool valid = i < N;
    float s = 0.f;
    int key = -1;
    if (valid) {
        int k = i >> BSHIFT, l = i & (BSIZE - 1);
        float2 self = pin[i];
        float ax = self.x, ay = self.y;
        for (int m = 0; m < M; ++m) {
            const float* pp = partial + ((size_t)(k * M + m)) * (BSIZE * 2) + 2 * l;
            ax += pp[0]; ay += pp[1];
        }
        float di = dinv[i];
        float h0 = fmaxf(fmaf(di, ax, b[0]), 0.f);
        float h1 = fmaxf(fmaf(di, ay, b[1]), 0.f);
        s = fmaf(h0, Wr[0], h1 * Wr[1]);
        key = batch[i];
    }
    int lane = threadIdx.x & 63;
    for (int off = 1; off < 64; off <<= 1) {
        float s2 = __shfl_down(s, off);
        int k2 = __shfl_down(key, off);
        if (lane + off < 64 && k2 == key) s += s2;
    }
    int kprev = __shfl_up(key, 1);
    if (valid && (lane == 0 || kprev != key)) unsafeAtomicAdd(&out[key], s);
}

// ---------------- launch ----------------

extern "C" void kernel_launch(void* const* d_in, const int* in_sizes, int n_in,
                              void* d_out, int out_size, void* d_ws, size_t ws_size,
                              hipStream_t stream) {
    const float* x    = (const float*)d_in[0];
    const int*   ei   = (const int*)d_in[1];
    const int*   batch= (const int*)d_in[2];
    const float* W1   = (const float*)d_in[3];
    const float* b1   = (const float*)d_in[4];
    const float* W2   = (const float*)d_in[5];
    const float* b2   = (const float*)d_in[6];
    const float* W3   = (const float*)d_in[7];
    const float* b3   = (const float*)d_in[8];
    const float* Wr   = (const float*)d_in[9];
    const float* br   = (const float*)d_in[10];
    float* out = (float*)d_out;

    int N = in_sizes[0] / 2;
    int E = in_sizes[1] / 2;
    int G = out_size;
    const int* src = ei;
    const int* dst = ei + E;

    int K = (N + BSIZE - 1) >> BSHIFT;
    if (K > KPAD) return;
    int S = NSLICE;
    int chunk = (E + S - 1) / S;

    int sbits = 1;
    while ((1 << sbits) < N) ++sbits;
    if (sbits + BSHIFT > 32) return;
    int smask = (1 << sbits) - 1;

    auto pad16 = [](size_t b) { return (b + 15) & ~(size_t)15; };
    size_t fixed = pad16((size_t)E * 4)                       // packed
                 + pad16((size_t)S * K * 4)                   // hpart
                 + pad16((size_t)(K + 1) * 4)                 // basep
                 + pad16((size_t)K * 4)                       // totals
                 + pad16((size_t)N * 4)                       // dinv
                 + 2 * pad16((size_t)N * 8);                  // pA, pB
    size_t lvl2 = pad16((size_t)E * 4)                        // packed2
                + pad16((size_t)K * R2 * BSIZE * 4);          // h2

    bool sorted = true;
    int M = 16;
    for (;;) {
        size_t need = fixed + pad16((size_t)K * M * BSIZE * 2 * 4) + (sorted ? lvl2 : 0);
        if (need <= ws_size) break;
        if (M > 4) { M >>= 1; continue; }
        if (sorted) { sorted = false; M = 16; continue; }
        if (M > 1) { M >>= 1; continue; }
        return;
    }

    char* w = (char*)d_ws;
    size_t off = 0;
    auto carve = [&](size_t bytes) { void* p = w + off; off += (bytes + 15) & ~(size_t)15; return p; };
    int*    packed  = (int*)carve((size_t)E * 4);
    int*    hpart   = (int*)carve((size_t)S * K * 4);
    int*    basep   = (int*)carve((size_t)(K + 1) * 4);
    int*    totals  = (int*)carve((size_t)K * 4);
    float*  aggpart = (float*)carve((size_t)K * M * BSIZE * 2 * 4);
    float*  dinv    = (float*)carve((size_t)N * 4);
    float2* pA      = (float2*)carve((size_t)N * 8);
    float2* pB      = (float2*)carve((size_t)N * 8);
    int*    packed2 = nullptr;
    int*    h2      = nullptr;
    if (sorted) {
        packed2 = (int*)carve((size_t)E * 4);
        h2      = (int*)carve((size_t)K * R2 * BSIZE * 4);
    }
    int* degpart = (int*)aggpart;            // reuse: consumed before first agg

    int NB = (N + BLK - 1) / BLK;
    int GB = (G + BLK - 1) / BLK;
    size_t smemK = (size_t)K * 4;
    int KM = K * M;

    // level-1 bucket build
    k_hist   <<<S, BLK, smemK, stream>>>(dst, hpart, E, chunk, K);
    k_colscan<<<K, NSLICE, 0, stream>>>(hpart, totals, K);
    k_base   <<<1, SCAN_T, 0, stream>>>(totals, basep, K);
    k_scatter<<<S, BLK, 0, stream>>>(src, dst, hpart, basep, packed, E, chunk, K, sbits);

    // degree -> dinv, p1
    k_deg   <<<KM, BLK, 0, stream>>>(packed, basep, M, degpart, sbits);
    k_node1 <<<NB, BLK, 0, stream>>>(degpart, M, x, W1, dinv, pA, N);

    if (sorted) {
        // level-2: full within-bucket sort by dst_local
        k_hist2   <<<K * R2, BLK, 0, stream>>>(packed, basep, h2, sbits);
        k_scan2   <<<K, BSIZE, 0, stream>>>(h2, basep);
        k_scatter3<<<K * R2, BLK, 0, stream>>>(packed, basep, h2, packed2, sbits);

        k_agg3    <<<KM, BLK, 0, stream>>>(packed2, basep, M, pA, aggpart, sbits, smask);
        k_node_mid<<<NB, BLK, 0, stream>>>(aggpart, M, dinv, pA, b1, W2, pB, N);
        k_agg3    <<<KM, BLK, 0, stream>>>(packed2, basep, M, pB, aggpart, sbits, smask);
        k_node_mid<<<NB, BLK, 0, stream>>>(aggpart, M, dinv, pB, b2, W3, pA, N);
        k_agg3    <<<KM, BLK, 0, stream>>>(packed2, basep, M, pA, aggpart, sbits, smask);
    } else {
        k_agg     <<<KM, BLK, 0, stream>>>(packed, basep, M, pA, aggpart, sbits, smask);
        k_node_mid<<<NB, BLK, 0, stream>>>(aggpart, M, dinv, pA, b1, W2, pB, N);
        k_agg     <<<KM, BLK, 0, stream>>>(packed, basep, M, pB, aggpart, sbits, smask);
        k_node_mid<<<NB, BLK, 0, stream>>>(aggpart, M, dinv, pB, b2, W3, pA, N);
        k_agg     <<<KM, BLK, 0, stream>>>(packed, basep, M, pA, aggpart, sbits, smask);
    }

    k_out_init<<<GB, BLK, 0, stream>>>(out, br, G);
    k_node_final<<<NB, BLK, 0, stream>>>(aggpart, M, dinv, pA, b3, Wr, batch, out, N);
}

// Round 14
// 517.391 us; speedup vs baseline: 1.3576x; 1.1451x over previous
//
#include <hip/hip_runtime.h>

#define BLK 256
#define BSHIFT 10
#define BSIZE 1024           // nodes per dst bucket (local index: 10 bits)
#define NSLICE 1024          // edge slices for hist/scatter
#define SCAN_T 512           // max K supported by single-block scan
#define KPAD 256             // max buckets (scan width in k_scatter)
#define EPT 8                // edges per thread per tile in scatter kernels
#define TILE (BLK * EPT)     // 2048 edges staged per tile
#define R2 8                 // sub-slices per bucket in within-bucket sort

typedef int iv4 __attribute__((ext_vector_type(4)));   // clang vector: nt-load legal

template <typename T>
__device__ __forceinline__ T ntload(const T* p) { return __builtin_nontemporal_load(p); }

__device__ __forceinline__ iv4 ntload4(const int* p) {
    return __builtin_nontemporal_load((const iv4*)p);
}

// ---------------- level-1: bucket by dst>>10 (no global atomics) ------------

__global__ void k_hist(const int* __restrict__ dst, int* __restrict__ partial,
                       int E, int chunk, int K) {
    extern __shared__ int cnt[];
    int s = blockIdx.x;
    for (int i = threadIdx.x; i < K; i += BLK) cnt[i] = 0;
    __syncthreads();
    int lo = s * chunk, hi = min(E, lo + chunk);
    for (int i = lo + threadIdx.x; i < hi; i += BLK)
        atomicAdd(&cnt[((unsigned)ntload(dst + i)) >> BSHIFT], 1);
    __syncthreads();
    int* prow = partial + (size_t)s * K;
    for (int i = threadIdx.x; i < K; i += BLK) prow[i] = cnt[i];
}

__global__ void __launch_bounds__(NSLICE) k_colscan(int* __restrict__ partial,
                                                    int* __restrict__ totals, int K) {
    __shared__ int sh[NSLICE];
    int k = blockIdx.x;
    int t = threadIdx.x;
    int v = partial[(size_t)t * K + k];
    sh[t] = v;
    __syncthreads();
    for (int off = 1; off < NSLICE; off <<= 1) {
        int u = (t >= off) ? sh[t - off] : 0;
        __syncthreads();
        sh[t] += u;
        __syncthreads();
    }
    partial[(size_t)t * K + k] = sh[t] - v;
    if (t == NSLICE - 1) totals[k] = sh[t];
}

__global__ void k_base(const int* __restrict__ totals, int* __restrict__ base, int K) {
    __shared__ int sh[SCAN_T];
    int t = threadIdx.x;
    int v = (t < K) ? totals[t] : 0;
    sh[t] = v;
    __syncthreads();
    for (int off = 1; off < SCAN_T; off <<= 1) {
        int u = (t >= off) ? sh[t - off] : 0;
        __syncthreads();
        sh[t] += u;
        __syncthreads();
    }
    if (t < K) base[t + 1] = sh[t];
    if (t == 0) base[0] = 0;
}

// tile counting-sort scatter: packed = (dst_local << sbits) | src
__global__ void __launch_bounds__(BLK) k_scatter(const int* __restrict__ src,
                                                 const int* __restrict__ dst,
                                                 const int* __restrict__ offs,
                                                 const int* __restrict__ base,
                                                 int* __restrict__ packed,
                                                 int E, int chunk, int K, int sbits) {
    __shared__ int cnt[KPAD];
    __shared__ int scn[KPAD];
    __shared__ int gstart[KPAD];
    __shared__ int cur[KPAD];
    __shared__ int stageval[TILE];
    __shared__ int stageaddr[TILE];
    int s = blockIdx.x;
    int tid = threadIdx.x;
    const int* orow = offs + (size_t)s * K;
    if (tid < K) cur[tid] = orow[tid] + base[tid];
    int lo = s * chunk, hi = min(E, lo + chunk);

    for (int tlo = lo; tlo < hi; tlo += TILE) {
        for (int k2 = tid; k2 < KPAD; k2 += BLK) cnt[k2] = 0;
        __syncthreads();

        int kk[EPT], rr[EPT], vv[EPT];
#pragma unroll
        for (int j = 0; j < EPT; ++j) {
            int i = tlo + j * BLK + tid;
            kk[j] = -1;
            if (i < hi) {
                int d = ntload(dst + i);
                int sc = ntload(src + i);
                kk[j] = ((unsigned)d) >> BSHIFT;
                vv[j] = ((d & (BSIZE - 1)) << sbits) | sc;
                rr[j] = atomicAdd(&cnt[kk[j]], 1);
            }
        }
        __syncthreads();

        int c = cnt[tid];
        scn[tid] = c;
        __syncthreads();
        for (int off = 1; off < KPAD; off <<= 1) {
            int u = (tid >= off) ? scn[tid - off] : 0;
            __syncthreads();
            scn[tid] += u;
            __syncthreads();
        }
        scn[tid] -= c;
        gstart[tid] = cur[tid];
        cur[tid] += c;
        __syncthreads();

#pragma unroll
        for (int j = 0; j < EPT; ++j) {
            if (kk[j] >= 0) {
                int idx = scn[kk[j]] + rr[j];
                stageval[idx]  = vv[j];
                stageaddr[idx] = gstart[kk[j]] + rr[j];
            }
        }
        __syncthreads();

        int tot = min(hi - tlo, TILE);
        for (int i2 = tid; i2 < tot; i2 += BLK)
            packed[stageaddr[i2]] = stageval[i2];
        __syncthreads();
    }
}

// ---------------- level-2: within-bucket sort, SLICE-MAJOR layout -----------
// output order per bucket: slice 0's bins 0..1023, slice 1's bins 0..1023, ...
// -> each scatter3 block writes a contiguous [s0,s1) window (write amp ~1)

// per (bucket, slice) histogram of dst_local -> h2[b][BSIZE]
__global__ void __launch_bounds__(BLK) k_hist2(const int* __restrict__ packed,
                                               const int* __restrict__ base,
                                               int* __restrict__ h2, int sbits) {
    __shared__ int cnt[BSIZE];
    int b = blockIdx.x;              // k*R2 + r
    int k = b / R2, r = b - k * R2;
    for (int i = threadIdx.x; i < BSIZE; i += BLK) cnt[i] = 0;
    __syncthreads();
    int lo = base[k], len = base[k + 1] - lo;
    int s0 = lo + (int)(((long long)len * r) / R2);
    int s1 = lo + (int)(((long long)len * (r + 1)) / R2);
    int a0 = min((s0 + 3) & ~3, s1);
    int a1 = max(s1 & ~3, a0);
    for (int i = s0 + threadIdx.x; i < a0; i += BLK)
        atomicAdd(&cnt[((unsigned)ntload(packed + i)) >> sbits], 1);
    for (int i = a0 + 4 * threadIdx.x; i < a1; i += 4 * BLK) {
        iv4 q = ntload4(packed + i);
        atomicAdd(&cnt[((unsigned)q.x) >> sbits], 1);
        atomicAdd(&cnt[((unsigned)q.y) >> sbits], 1);
        atomicAdd(&cnt[((unsigned)q.z) >> sbits], 1);
        atomicAdd(&cnt[((unsigned)q.w) >> sbits], 1);
    }
    for (int i = a1 + threadIdx.x; i < s1; i += BLK)
        atomicAdd(&cnt[((unsigned)ntload(packed + i)) >> sbits], 1);
    __syncthreads();
    int* hrow = h2 + (size_t)b * BSIZE;
    for (int i = threadIdx.x; i < BSIZE; i += BLK) hrow[i] = cnt[i];
}

// per-(bucket,slice) scan: h2 row -> absolute slice-major offsets (s0 + excl prefix)
// side-output: degN[node] += count (degree accumulation, replaces k_deg)
__global__ void __launch_bounds__(BLK) k_scan2(int* __restrict__ h2,
                                               const int* __restrict__ base,
                                               int* __restrict__ degN) {
    __shared__ int tsum[BLK];
    int b = blockIdx.x;              // k*R2 + r
    int k = b / R2, r = b - k * R2;
    int tid = threadIdx.x;
    int* row = h2 + (size_t)b * BSIZE;
    int c0 = row[4 * tid], c1 = row[4 * tid + 1],
        c2 = row[4 * tid + 2], c3 = row[4 * tid + 3];
    int sum = c0 + c1 + c2 + c3;
    tsum[tid] = sum;
    __syncthreads();
    for (int off = 1; off < BLK; off <<= 1) {
        int u = (tid >= off) ? tsum[tid - off] : 0;
        __syncthreads();
        tsum[tid] += u;
        __syncthreads();
    }
    int lo = base[k], len = base[k + 1] - lo;
    int s0 = lo + (int)(((long long)len * r) / R2);
    int run = s0 + tsum[tid] - sum;
    row[4 * tid]     = run;
    row[4 * tid + 1] = run + c0;
    row[4 * tid + 2] = run + c0 + c1;
    row[4 * tid + 3] = run + c0 + c1 + c2;
    int nb = (k << BSHIFT) + 4 * tid;
    if (c0) atomicAdd(&degN[nb], c0);
    if (c1) atomicAdd(&degN[nb + 1], c1);
    if (c2) atomicAdd(&degN[nb + 2], c2);
    if (c3) atomicAdd(&degN[nb + 3], c3);
}

// counting-sort each (bucket, slice) by dst_local into its contiguous window
__global__ void __launch_bounds__(BLK) k_scatter3(const int* __restrict__ packed,
                                                  const int* __restrict__ base,
                                                  const int* __restrict__ h2,
                                                  int* __restrict__ packed2, int sbits) {
    __shared__ int cnt[BSIZE];
    __shared__ int cur[BSIZE];
    __shared__ int gstart[BSIZE];
    __shared__ int tsum[BLK];
    __shared__ int sval[TILE];
    __shared__ int sadr[TILE];
    int b = blockIdx.x;              // k*R2 + r
    int k = b / R2, r = b - k * R2;
    int tid = threadIdx.x;
    const int* hrow = h2 + (size_t)b * BSIZE;
    for (int i = tid; i < BSIZE; i += BLK) cur[i] = hrow[i];
    int lo = base[k], len = base[k + 1] - lo;
    int s0 = lo + (int)(((long long)len * r) / R2);
    int s1 = lo + (int)(((long long)len * (r + 1)) / R2);

    for (int tlo = s0; tlo < s1; tlo += TILE) {
        for (int i = tid; i < BSIZE; i += BLK) cnt[i] = 0;
        __syncthreads();

        int kk[EPT], rr[EPT], vv[EPT];
#pragma unroll
        for (int j = 0; j < EPT; ++j) {
            int i = tlo + j * BLK + tid;
            kk[j] = -1;
            if (i < s1) {
                int v = ntload(packed + i);
                vv[j] = v;
                kk[j] = ((unsigned)v) >> sbits;
                rr[j] = atomicAdd(&cnt[kk[j]], 1);
            }
        }
        __syncthreads();

        // scan over 1024 bins: 4 bins/thread + 256-wide block scan
        int c0 = cnt[4 * tid], c1 = cnt[4 * tid + 1],
            c2 = cnt[4 * tid + 2], c3 = cnt[4 * tid + 3];
        int sum = c0 + c1 + c2 + c3;
        tsum[tid] = sum;
        __syncthreads();
        for (int off = 1; off < BLK; off <<= 1) {
            int u = (tid >= off) ? tsum[tid - off] : 0;
            __syncthreads();
            tsum[tid] += u;
            __syncthreads();
        }
        int runb = tsum[tid] - sum;  // exclusive
        gstart[4 * tid]     = cur[4 * tid];     cur[4 * tid]     += c0;
        gstart[4 * tid + 1] = cur[4 * tid + 1]; cur[4 * tid + 1] += c1;
        gstart[4 * tid + 2] = cur[4 * tid + 2]; cur[4 * tid + 2] += c2;
        gstart[4 * tid + 3] = cur[4 * tid + 3]; cur[4 * tid + 3] += c3;
        cnt[4 * tid]     = runb;
        cnt[4 * tid + 1] = runb + c0;
        cnt[4 * tid + 2] = runb + c0 + c1;
        cnt[4 * tid + 3] = runb + c0 + c1 + c2;
        __syncthreads();

#pragma unroll
        for (int j = 0; j < EPT; ++j) {
            if (kk[j] >= 0) {
                int idx = cnt[kk[j]] + rr[j];
                sval[idx] = vv[j];
                sadr[idx] = gstart[kk[j]] + rr[j];
            }
        }
        __syncthreads();

        int tot = min(s1 - tlo, TILE);
        for (int i2 = tid; i2 < tot; i2 += BLK)
            packed2[sadr[i2]] = sval[i2];
        __syncthreads();
    }
}

// ---------------- aggregation ----------------

// fallback degree kernel (unsorted path only)
__global__ void k_deg(const int* __restrict__ packed, const int* __restrict__ base,
                      int M, int* __restrict__ degpart, int sbits) {
    __shared__ int cnt[BSIZE];
    int b = blockIdx.x;
    int k = b / M, m = b - k * M;
    for (int i = threadIdx.x; i < BSIZE; i += BLK) cnt[i] = 0;
    __syncthreads();
    int lo = base[k], len = base[k + 1] - lo;
    int l0 = lo + (int)(((long long)len * m) / M);
    int l1 = lo + (int)(((long long)len * (m + 1)) / M);
    for (int i = l0 + threadIdx.x; i < l1; i += BLK)
        atomicAdd(&cnt[((unsigned)ntload(packed + i)) >> sbits], 1);
    __syncthreads();
    int* outp = degpart + (size_t)b * BSIZE;
    for (int i = threadIdx.x; i < BSIZE; i += BLK) outp[i] = cnt[i];
}

// sorted-edge agg: 64-edge windows, segmented shfl suffix-reduce, atomics only at heads
__global__ void __launch_bounds__(BLK) k_agg3(const int* __restrict__ packed2,
                                              const int* __restrict__ base,
                                              int M, const float2* __restrict__ pin,
                                              float* __restrict__ partial,
                                              int sbits, int smask) {
    __shared__ float accx[BSIZE];
    __shared__ float accy[BSIZE];
    int b = blockIdx.x;
    int k = b / M, m = b - k * M;
    for (int i = threadIdx.x; i < BSIZE; i += BLK) { accx[i] = 0.f; accy[i] = 0.f; }
    __syncthreads();
    int lo = base[k], len = base[k + 1] - lo;
    int l0 = lo + (int)(((long long)len * m) / M);
    int l1 = lo + (int)(((long long)len * (m + 1)) / M);
    int lane = threadIdx.x & 63;
    int wid = threadIdx.x >> 6;              // 4 waves per block

    for (int wbase = l0 + wid * 64; wbase < l1; wbase += 4 * 64) {
        int i = wbase + lane;
        bool valid = i < l1;
        unsigned v = valid ? (unsigned)ntload(packed2 + i) : 0u;
        int key = valid ? (int)(v >> sbits) : -1;
        float sx = 0.f, sy = 0.f;
        if (valid) {
            float2 e = pin[v & smask];       // the one random gather
            sx = e.x; sy = e.y;
        }
        // segmented suffix sum over sorted keys
        for (int off = 1; off < 64; off <<= 1) {
            float x2 = __shfl_down(sx, off);
            float y2 = __shfl_down(sy, off);
            int  k2 = __shfl_down(key, off);
            if (lane + off < 64 && k2 == key) { sx += x2; sy += y2; }
        }
        int kprev = __shfl_up(key, 1);
        if (valid && (lane == 0 || kprev != key)) {
            atomicAdd(&accx[key], sx);
            atomicAdd(&accy[key], sy);
        }
    }
    __syncthreads();
    float* outp = partial + (size_t)b * (BSIZE * 2);
    for (int j = threadIdx.x * 2; j < BSIZE; j += BLK * 2) {
        float4 o = make_float4(accx[j], accy[j], accx[j + 1], accy[j + 1]);
        *(float4*)(outp + 2 * j) = o;
    }
}

// fallback: unsorted gather agg (4-wide) when ws too small for level-2
__global__ void __launch_bounds__(BLK) k_agg(const int* __restrict__ packed,
                                             const int* __restrict__ base,
                                             int M, const float2* __restrict__ pin,
                                             float* __restrict__ partial,
                                             int sbits, int smask) {
    __shared__ float accx[BSIZE];
    __shared__ float accy[BSIZE];
    int b = blockIdx.x;
    int k = b / M, m = b - k * M;
    for (int i = threadIdx.x; i < BSIZE; i += BLK) { accx[i] = 0.f; accy[i] = 0.f; }
    __syncthreads();
    int lo = base[k], len = base[k + 1] - lo;
    int l0 = lo + (int)(((long long)len * m) / M);
    int l1 = lo + (int)(((long long)len * (m + 1)) / M);
    int a0 = min((l0 + 3) & ~3, l1);
    int a1 = max(l1 & ~3, a0);
    for (int i = l0 + threadIdx.x; i < a0; i += BLK) {
        unsigned v = (unsigned)ntload(packed + i);
        float2 pv = pin[v & smask];
        int l = v >> sbits;
        atomicAdd(&accx[l], pv.x);
        atomicAdd(&accy[l], pv.y);
    }
    for (int i = a0 + 4 * threadIdx.x; i < a1; i += 4 * BLK) {
        iv4 q = ntload4(packed + i);
        unsigned v0 = q.x, v1 = q.y, v2 = q.z, v3 = q.w;
        float2 e0 = pin[v0 & smask];
        float2 e1 = pin[v1 & smask];
        float2 e2 = pin[v2 & smask];
        float2 e3 = pin[v3 & smask];
        int l0i = v0 >> sbits, l1i = v1 >> sbits, l2i = v2 >> sbits, l3i = v3 >> sbits;
        atomicAdd(&accx[l0i], e0.x); atomicAdd(&accy[l0i], e0.y);
        atomicAdd(&accx[l1i], e1.x); atomicAdd(&accy[l1i], e1.y);
        atomicAdd(&accx[l2i], e2.x); atomicAdd(&accy[l2i], e2.y);
        atomicAdd(&accx[l3i], e3.x); atomicAdd(&accy[l3i], e3.y);
    }
    for (int j = a1 + threadIdx.x; j < l1; j += BLK) {
        unsigned v = (unsigned)ntload(packed + j);
        float2 pv = pin[v & smask];
        int l = v >> sbits;
        atomicAdd(&accx[l], pv.x);
        atomicAdd(&accy[l], pv.y);
    }
    __syncthreads();
    float* outp = partial + (size_t)b * (BSIZE * 2);
    for (int j = threadIdx.x * 2; j < BSIZE; j += BLK * 2) {
        float4 o = make_float4(accx[j], accy[j], accx[j + 1], accy[j + 1]);
        *(float4*)(outp + 2 * j) = o;
    }
}

// ---------------- node epilogues ----------------

// degree from degN (sorted path)
__global__ void k_node1c(const int* __restrict__ degN, const float* __restrict__ x,
                         const float* __restrict__ W1, float* __restrict__ dinv,
                         float2* __restrict__ p1, int N) {
    int i = blockIdx.x * BLK + threadIdx.x;
    if (i >= N) return;
    float di = rsqrtf((float)degN[i] + 1.0f);
    dinv[i] = di;
    float2 xv = ((const float2*)x)[i];
    float w00 = W1[0], w01 = W1[1], w10 = W1[2], w11 = W1[3];
    p1[i] = make_float2(di * (xv.x * w00 + xv.y * w10),
                        di * (xv.x * w01 + xv.y * w11));
}

// degree from degpart (fallback path)
__global__ void k_node1(const int* __restrict__ degpart, int M,
                        const float* __restrict__ x, const float* __restrict__ W1,
                        float* __restrict__ dinv, float2* __restrict__ p1, int N) {
    int i = blockIdx.x * BLK + threadIdx.x;
    if (i >= N) return;
    int k = i >> BSHIFT, l = i & (BSIZE - 1);
    int c = 0;
    for (int m = 0; m < M; ++m) c += degpart[((size_t)(k * M + m)) * BSIZE + l];
    float di = rsqrtf((float)c + 1.0f);
    dinv[i] = di;
    float2 xv = ((const float2*)x)[i];
    float w00 = W1[0], w01 = W1[1], w10 = W1[2], w11 = W1[3];
    p1[i] = make_float2(di * (xv.x * w00 + xv.y * w10),
                        di * (xv.x * w01 + xv.y * w11));
}

__global__ void k_node_mid(const float* __restrict__ partial, int M,
                           const float* __restrict__ dinv, const float2* __restrict__ pin,
                           const float* __restrict__ b, const float* __restrict__ W,
                           float2* __restrict__ pout, int N) {
    int i = blockIdx.x * BLK + threadIdx.x;
    if (i >= N) return;
    int k = i >> BSHIFT, l = i & (BSIZE - 1);
    float2 self = pin[i];
    float ax = self.x, ay = self.y;
    for (int m = 0; m < M; ++m) {
        const float* pp = partial + ((size_t)(k * M + m)) * (BSIZE * 2) + 2 * l;
        ax += pp[0]; ay += pp[1];
    }
    float di = dinv[i];
    float h0 = fmaxf(fmaf(di, ax, b[0]), 0.f);
    float h1 = fmaxf(fmaf(di, ay, b[1]), 0.f);
    float w00 = W[0], w01 = W[1], w10 = W[2], w11 = W[3];
    pout[i] = make_float2(di * (h0 * w00 + h1 * w10),
                          di * (h0 * w01 + h1 * w11));
}

__global__ void k_out_init(float* __restrict__ out, const float* __restrict__ br, int G) {
    int i = blockIdx.x * BLK + threadIdx.x;
    if (i < G) out[i] = br[0];
}

__global__ void k_node_final(const float* __restrict__ partial, int M,
                             const float* __restrict__ dinv, const float2* __restrict__ pin,
                             const float* __restrict__ b, const float* __restrict__ Wr,
                             const int* __restrict__ batch, float* __restrict__ out, int N) {
    int i = blockIdx.x * BLK + threadIdx.x;
    bool valid = i < N;
    float s = 0.f;
    int key = -1;
    if (valid) {
        int k = i >> BSHIFT, l = i & (BSIZE - 1);
        float2 self = pin[i];
        float ax = self.x, ay = self.y;
        for (int m = 0; m < M; ++m) {
            const float* pp = partial + ((size_t)(k * M + m)) * (BSIZE * 2) + 2 * l;
            ax += pp[0]; ay += pp[1];
        }
        float di = dinv[i];
        float h0 = fmaxf(fmaf(di, ax, b[0]), 0.f);
        float h1 = fmaxf(fmaf(di, ay, b[1]), 0.f);
        s = fmaf(h0, Wr[0], h1 * Wr[1]);
        key = batch[i];
    }
    int lane = threadIdx.x & 63;
    for (int off = 1; off < 64; off <<= 1) {
        float s2 = __shfl_down(s, off);
        int k2 = __shfl_down(key, off);
        if (lane + off < 64 && k2 == key) s += s2;
    }
    int kprev = __shfl_up(key, 1);
    if (valid && (lane == 0 || kprev != key)) unsafeAtomicAdd(&out[key], s);
}

// ---------------- launch ----------------

extern "C" void kernel_launch(void* const* d_in, const int* in_sizes, int n_in,
                              void* d_out, int out_size, void* d_ws, size_t ws_size,
                              hipStream_t stream) {
    const float* x    = (const float*)d_in[0];
    const int*   ei   = (const int*)d_in[1];
    const int*   batch= (const int*)d_in[2];
    const float* W1   = (const float*)d_in[3];
    const float* b1   = (const float*)d_in[4];
    const float* W2   = (const float*)d_in[5];
    const float* b2   = (const float*)d_in[6];
    const float* W3   = (const float*)d_in[7];
    const float* b3   = (const float*)d_in[8];
    const float* Wr   = (const float*)d_in[9];
    const float* br   = (const float*)d_in[10];
    float* out = (float*)d_out;

    int N = in_sizes[0] / 2;
    int E = in_sizes[1] / 2;
    int G = out_size;
    const int* src = ei;
    const int* dst = ei + E;

    int K = (N + BSIZE - 1) >> BSHIFT;
    if (K > KPAD) return;
    int S = NSLICE;
    int chunk = (E + S - 1) / S;

    int sbits = 1;
    while ((1 << sbits) < N) ++sbits;
    if (sbits + BSHIFT > 32) return;
    int smask = (1 << sbits) - 1;

    auto pad16 = [](size_t b) { return (b + 15) & ~(size_t)15; };
    size_t fixed = pad16((size_t)E * 4)                       // packed
                 + pad16((size_t)S * K * 4)                   // hpart
                 + pad16((size_t)(K + 1) * 4)                 // basep
                 + pad16((size_t)K * 4)                       // totals
                 + pad16((size_t)N * 4)                       // dinv
                 + 2 * pad16((size_t)N * 8);                  // pA, pB
    size_t lvl2 = pad16((size_t)E * 4)                        // packed2
                + pad16((size_t)K * R2 * BSIZE * 4)           // h2
                + pad16((size_t)K * BSIZE * 4);               // degN

    bool sorted = true;
    int M = 16;
    for (;;) {
        size_t need = fixed + pad16((size_t)K * M * BSIZE * 2 * 4) + (sorted ? lvl2 : 0);
        if (need <= ws_size) break;
        if (M > 4) { M >>= 1; continue; }
        if (sorted) { sorted = false; M = 16; continue; }
        if (M > 1) { M >>= 1; continue; }
        return;
    }

    char* w = (char*)d_ws;
    size_t off = 0;
    auto carve = [&](size_t bytes) { void* p = w + off; off += (bytes + 15) & ~(size_t)15; return p; };
    int*    packed  = (int*)carve((size_t)E * 4);
    int*    hpart   = (int*)carve((size_t)S * K * 4);
    int*    basep   = (int*)carve((size_t)(K + 1) * 4);
    int*    totals  = (int*)carve((size_t)K * 4);
    float*  aggpart = (float*)carve((size_t)K * M * BSIZE * 2 * 4);
    float*  dinv    = (float*)carve((size_t)N * 4);
    float2* pA      = (float2*)carve((size_t)N * 8);
    float2* pB      = (float2*)carve((size_t)N * 8);
    int*    packed2 = nullptr;
    int*    h2      = nullptr;
    int*    degN    = nullptr;
    if (sorted) {
        packed2 = (int*)carve((size_t)E * 4);
        h2      = (int*)carve((size_t)K * R2 * BSIZE * 4);
        degN    = (int*)carve((size_t)K * BSIZE * 4);
    }
    int* degpart = (int*)aggpart;            // fallback only: consumed before first agg

    int NB = (N + BLK - 1) / BLK;
    int GB = (G + BLK - 1) / BLK;
    size_t smemK = (size_t)K * 4;
    int KM = K * M;

    // level-1 bucket build
    k_hist   <<<S, BLK, smemK, stream>>>(dst, hpart, E, chunk, K);
    k_colscan<<<K, NSLICE, 0, stream>>>(hpart, totals, K);
    k_base   <<<1, SCAN_T, 0, stream>>>(totals, basep, K);
    k_scatter<<<S, BLK, 0, stream>>>(src, dst, hpart, basep, packed, E, chunk, K, sbits);

    if (sorted) {
        // level-2: slice-major within-bucket sort + degree accumulation
        hipMemsetAsync(degN, 0, (size_t)K * BSIZE * 4, stream);
        k_hist2   <<<K * R2, BLK, 0, stream>>>(packed, basep, h2, sbits);
        k_scan2   <<<K * R2, BLK, 0, stream>>>(h2, basep, degN);
        k_scatter3<<<K * R2, BLK, 0, stream>>>(packed, basep, h2, packed2, sbits);
        k_node1c  <<<NB, BLK, 0, stream>>>(degN, x, W1, dinv, pA, N);

        k_agg3    <<<KM, BLK, 0, stream>>>(packed2, basep, M, pA, aggpart, sbits, smask);
        k_node_mid<<<NB, BLK, 0, stream>>>(aggpart, M, dinv, pA, b1, W2, pB, N);
        k_agg3    <<<KM, BLK, 0, stream>>>(packed2, basep, M, pB, aggpart, sbits, smask);
        k_node_mid<<<NB, BLK, 0, stream>>>(aggpart, M, dinv, pB, b2, W3, pA, N);
        k_agg3    <<<KM, BLK, 0, stream>>>(packed2, basep, M, pA, aggpart, sbits, smask);
    } else {
        k_deg     <<<KM, BLK, 0, stream>>>(packed, basep, M, degpart, sbits);
        k_node1   <<<NB, BLK, 0, stream>>>(degpart, M, x, W1, dinv, pA, N);
        k_agg     <<<KM, BLK, 0, stream>>>(packed, basep, M, pA, aggpart, sbits, smask);
        k_node_mid<<<NB, BLK, 0, stream>>>(aggpart, M, dinv, pA, b1, W2, pB, N);
        k_agg     <<<KM, BLK, 0, stream>>>(packed, basep, M, pB, aggpart, sbits, smask);
        k_node_mid<<<NB, BLK, 0, stream>>>(aggpart, M, dinv, pB, b2, W3, pA, N);
        k_agg     <<<KM, BLK, 0, stream>>>(packed, basep, M, pA, aggpart, sbits, smask);
    }

    k_out_init<<<GB, BLK, 0, stream>>>(out, br, G);
    k_node_final<<<NB, BLK, 0, stream>>>(aggpart, M, dinv, pA, b3, Wr, batch, out, N);
}